// Round 1
// baseline (1629.557 us; speedup 1.0000x reference)
//
#include <hip/hip_runtime.h>
#include <math.h>

// Problem constants (from reference)
constexpr int N_NODES = 50000;
constexpr int N_EDGES = 1600000;
constexpr int HDIM    = 64;
constexpr int NLAYER  = 5;
constexpr int NBASIS  = 8;
constexpr int TLUT    = 2048;          // radial LUT entries per layer
constexpr float CUT_R = 5.0f;
constexpr float PI_F  = 3.14159265358979f;

__device__ __forceinline__ float bcastf(float v, int l) {
    return __uint_as_float(__builtin_amdgcn_readlane(__float_as_uint(v), l));
}
__device__ __forceinline__ float waveRedSum(float v) {
    for (int off = 32; off > 0; off >>= 1) v += __shfl_xor(v, off, 64);
    return v;
}
__device__ __forceinline__ float siluf(float x) { return x / (1.0f + __expf(-x)); }

// ---------------- setup kernels ----------------

__global__ void k_embed(const int* __restrict__ an, const float* __restrict__ embed,
                        float* __restrict__ feats) {
    int i = blockIdx.x * blockDim.x + threadIdx.x;           // N*H threads
    if (i >= N_NODES * HDIM) return;
    int node = i >> 6, h = i & 63;
    feats[i] = embed[an[node] * HDIM + h];
}

__global__ void k_hist(const int* __restrict__ row, int* __restrict__ counts) {
    int e = blockIdx.x * blockDim.x + threadIdx.x;
    if (e < N_EDGES) atomicAdd(&counts[row[e]], 1);
}

__global__ void k_scan1(const int* __restrict__ counts, int* __restrict__ partial) {
    __shared__ int s[256];
    int i = blockIdx.x * 256 + threadIdx.x;
    int v = (i < N_NODES) ? counts[i] : 0;
    s[threadIdx.x] = v; __syncthreads();
    for (int off = 128; off > 0; off >>= 1) {
        if (threadIdx.x < off) s[threadIdx.x] += s[threadIdx.x + off];
        __syncthreads();
    }
    if (threadIdx.x == 0) partial[blockIdx.x] = s[0];
}

__global__ void k_scan2(int* __restrict__ partial, int nb) {
    if (threadIdx.x == 0 && blockIdx.x == 0) {
        int run = 0;
        for (int b = 0; b < nb; ++b) { int v = partial[b]; partial[b] = run; run += v; }
    }
}

__global__ void k_scan3(const int* __restrict__ counts, const int* __restrict__ partial,
                        int* __restrict__ starts, int* __restrict__ cursor) {
    __shared__ int s[256];
    int i = blockIdx.x * 256 + threadIdx.x;
    int v = (i < N_NODES) ? counts[i] : 0;
    s[threadIdx.x] = v; __syncthreads();
    for (int off = 1; off < 256; off <<= 1) {               // inclusive Hillis-Steele
        int add = (threadIdx.x >= off) ? s[threadIdx.x - off] : 0;
        __syncthreads();
        s[threadIdx.x] += add;
        __syncthreads();
    }
    if (i < N_NODES) {
        int st = partial[blockIdx.x] + s[threadIdx.x] - v;  // exclusive
        starts[i] = st; cursor[i] = st;
    }
    if (i == 0) starts[N_NODES] = N_EDGES;
}

__global__ void k_scatter(const int* __restrict__ row, const int* __restrict__ col,
                          const float* __restrict__ pos, int* __restrict__ cursor,
                          int* __restrict__ col_perm, float* __restrict__ tpos_perm) {
    int e = blockIdx.x * blockDim.x + threadIdx.x;
    if (e >= N_EDGES) return;
    int r = row[e], c = col[e];
    int p = atomicAdd(&cursor[r], 1);
    float dx = pos[c * 3 + 0] - pos[r * 3 + 0];
    float dy = pos[c * 3 + 1] - pos[r * 3 + 1];
    float dz = pos[c * 3 + 2] - pos[r * 3 + 2];
    float len = sqrtf(dx * dx + dy * dy + dz * dz);
    float t = len * ((float)(TLUT - 1) / CUT_R);
    t = fminf(t, (float)(TLUT - 1));
    col_perm[p]  = c;
    tpos_perm[p] = t;
}

// W2s[l][k][h] = sum_{m<3} rad_w2[l][k][h*3+m]
__global__ void k_w2s(const float* __restrict__ rad_w2, float* __restrict__ W2s) {
    int i = blockIdx.x * blockDim.x + threadIdx.x;          // L*H*H
    if (i >= NLAYER * HDIM * HDIM) return;
    int l = i / (HDIM * HDIM); int rem = i % (HDIM * HDIM);
    int k = rem / HDIM; int h = rem % HDIM;
    const float* w = rad_w2 + ((size_t)l * HDIM + k) * (HDIM * 3) + h * 3;
    W2s[i] = w[0] + w[1] + w[2];
}

// Wsp[l][k][h] = sum_m self_w[l][k][m] * proj_w[l][m][h]   (proj top half)
__global__ void k_wsp(const float* __restrict__ self_w, const float* __restrict__ proj_w,
                      float* __restrict__ Wsp) {
    int i = blockIdx.x * blockDim.x + threadIdx.x;          // L*H*H
    if (i >= NLAYER * HDIM * HDIM) return;
    int l = i / (HDIM * HDIM); int rem = i % (HDIM * HDIM);
    int k = rem / HDIM; int h = rem % HDIM;
    const float* sw = self_w + ((size_t)l * HDIM + k) * HDIM;
    const float* pw = proj_w + (size_t)l * 2 * HDIM * HDIM;
    float acc = 0.f;
    for (int m = 0; m < HDIM; ++m) acc += sw[m] * pw[m * HDIM + h];
    Wsp[i] = acc;
}

// b2s[l][h] = sum_m rad_b2[l][h*3+m];  bsp[l][h] = sum_m self_b[l][m]*proj_w[l][m][h] + proj_b[l][h]
__global__ void k_bias(const float* __restrict__ rad_b2, const float* __restrict__ self_b,
                       const float* __restrict__ proj_w, const float* __restrict__ proj_b,
                       float* __restrict__ b2s, float* __restrict__ bsp) {
    int i = blockIdx.x * blockDim.x + threadIdx.x;          // L*H
    if (i >= NLAYER * HDIM) return;
    int l = i / HDIM, h = i % HDIM;
    const float* rb2 = rad_b2 + l * HDIM * 3 + h * 3;
    b2s[i] = rb2[0] + rb2[1] + rb2[2];
    float acc = proj_b[l * HDIM + h];
    const float* pw = proj_w + (size_t)l * 2 * HDIM * HDIM;
    const float* sb = self_b + l * HDIM;
    for (int m = 0; m < HDIM; ++m) acc += sb[m] * pw[m * HDIM + h];
    bsp[i] = acc;
}

// radial LUT: lut[l][t][h] = (silu(rbf(len_t)@W1 + b1) @ W2s + b2s)[h]
__global__ void k_lut(const float* __restrict__ widths, const float* __restrict__ rad_w1,
                      const float* __restrict__ rad_b1, const float* __restrict__ W2s,
                      const float* __restrict__ b2s, float* __restrict__ lut) {
    int bid = blockIdx.x;                 // l*TLUT + t
    int l = bid / TLUT, t = bid % TLUT;
    int h = threadIdx.x;                  // 64 threads
    __shared__ float h1s[HDIM];
    float len = (float)t * (CUT_R / (float)(TLUT - 1));
    float cut = 0.0f;
    if (len < CUT_R) cut = 0.5f * (cosf(len * (PI_F / CUT_R)) + 1.0f);
    float acc = rad_b1[l * HDIM + h];
    for (int b = 0; b < NBASIS; ++b) {
        float wb = fmaxf(widths[b], 0.1f);
        float center = (float)b * (CUT_R / (float)(NBASIS - 1));
        float d = (len - center) / wb;
        float rbf = __expf(-0.5f * d * d) * cut;
        acc += rbf * rad_w1[(l * NBASIS + b) * HDIM + h];
    }
    h1s[h] = siluf(acc);
    __syncthreads();
    float o = b2s[l * HDIM + h];
    const float* w2 = W2s + (size_t)l * HDIM * HDIM;
    for (int k = 0; k < HDIM; ++k) o += h1s[k] * w2[k * HDIM + h];
    lut[(size_t)bid * HDIM + h] = o;
}

// ---------------- per-layer kernels ----------------

// one wave per node: agg[i][h] = sum_{e in CSR(i)} feats[col[e]][h] * LUT(len_e)[h]
__global__ __launch_bounds__(256) void k_agg(const float* __restrict__ feats,
                                             const float* __restrict__ lut_l,
                                             const int* __restrict__ starts,
                                             const int* __restrict__ col_perm,
                                             const float* __restrict__ tpos_perm,
                                             float* __restrict__ agg) {
    int wid  = (blockIdx.x * blockDim.x + threadIdx.x) >> 6;
    int lane = threadIdx.x & 63;
    if (wid >= N_NODES) return;
    int e0 = starts[wid], e1 = starts[wid + 1];
    float acc = 0.0f;
    for (int e = e0; e < e1; ++e) {
        int   c = col_perm[e];
        float t = tpos_perm[e];
        int   i0 = (int)t;
        float f  = t - (float)i0;
        const float* lr = lut_l + (size_t)i0 * HDIM;
        float w0 = lr[lane];
        float w1 = lr[(i0 < TLUT - 1 ? HDIM : 0) + lane];
        float wv = w0 + f * (w1 - w0);
        acc += feats[(size_t)c * HDIM + lane] * wv;
    }
    agg[(size_t)wid * HDIM + lane] = acc;
}

// one wave per 8 nodes: conv -> mlp -> residual+LN, weights broadcast via readlane
constexpr int NT = 8;
__global__ __launch_bounds__(256) void k_node(float* __restrict__ feats,
        const float* __restrict__ agg,
        const float* __restrict__ Wsp_l, const float* __restrict__ bsp_l,
        const float* __restrict__ projw_l,
        const float* __restrict__ mlp_w1_l, const float* __restrict__ mlp_b1_l,
        const float* __restrict__ mlp_w2_l, const float* __restrict__ mlp_b2_l,
        const float* __restrict__ ln_g_l, const float* __restrict__ ln_b_l) {
    int wid  = (blockIdx.x * blockDim.x + threadIdx.x) >> 6;
    int lane = threadIdx.x & 63;
    int base = wid * NT;
    if (base >= N_NODES) return;
    const float* pb = projw_l + HDIM * HDIM;   // bottom half of proj_w

    float x[NT], a[NT];
    #pragma unroll
    for (int n = 0; n < NT; ++n) {
        int node = base + n;
        if (node < N_NODES) {
            x[n] = feats[(size_t)node * HDIM + lane];
            a[n] = agg[(size_t)node * HDIM + lane];
        } else { x[n] = 0.f; a[n] = 0.f; }
    }

    float conv[NT];
    float bspv = bsp_l[lane];
    #pragma unroll
    for (int n = 0; n < NT; ++n) conv[n] = bspv;
    #pragma unroll 8
    for (int k = 0; k < HDIM; ++k) {
        float wk = Wsp_l[k * HDIM + lane];
        float pk = pb[k * HDIM + lane];
        #pragma unroll
        for (int n = 0; n < NT; ++n) {
            conv[n] += bcastf(x[n], k) * wk + bcastf(a[n], k) * pk;
        }
    }

    float m1a[NT], m1b[NT];
    {
        float b1a = mlp_b1_l[lane], b1b = mlp_b1_l[HDIM + lane];
        #pragma unroll
        for (int n = 0; n < NT; ++n) { m1a[n] = b1a; m1b[n] = b1b; }
    }
    #pragma unroll 8
    for (int k = 0; k < HDIM; ++k) {
        float w1a = mlp_w1_l[k * 2 * HDIM + lane];
        float w1b = mlp_w1_l[k * 2 * HDIM + HDIM + lane];
        #pragma unroll
        for (int n = 0; n < NT; ++n) {
            float ck = bcastf(conv[n], k);
            m1a[n] += ck * w1a;
            m1b[n] += ck * w1b;
        }
    }
    #pragma unroll
    for (int n = 0; n < NT; ++n) { m1a[n] = siluf(m1a[n]); m1b[n] = siluf(m1b[n]); }

    float upd[NT];
    {
        float b2v = mlp_b2_l[lane];
        #pragma unroll
        for (int n = 0; n < NT; ++n) upd[n] = b2v;
    }
    #pragma unroll 8
    for (int j = 0; j < HDIM; ++j) {
        float w2a = mlp_w2_l[j * HDIM + lane];
        float w2b = mlp_w2_l[(HDIM + j) * HDIM + lane];
        #pragma unroll
        for (int n = 0; n < NT; ++n) {
            upd[n] += bcastf(m1a[n], j) * w2a + bcastf(m1b[n], j) * w2b;
        }
    }

    float gv = ln_g_l[lane], bv = ln_b_l[lane];
    #pragma unroll
    for (int n = 0; n < NT; ++n) {
        float y  = x[n] + upd[n];
        float s1 = waveRedSum(y);
        float s2 = waveRedSum(y * y);
        float mu  = s1 * (1.0f / HDIM);
        float var = s2 * (1.0f / HDIM) - mu * mu;
        float r = rsqrtf(var + 1e-5f);
        int node = base + n;
        if (node < N_NODES)
            feats[(size_t)node * HDIM + lane] = (y - mu) * r * gv + bv;
    }
}

// ---------------- readout ----------------

__global__ __launch_bounds__(256) void k_readout(const float* __restrict__ feats,
        const int* __restrict__ an,
        const float* __restrict__ ro_w1, const float* __restrict__ ro_b1,
        const float* __restrict__ ro_w2, const float* __restrict__ ro_b2,
        const float* __restrict__ ro_w3, const float* __restrict__ ro_b3,
        const float* __restrict__ atomic_e, float* __restrict__ blockpart) {
    __shared__ float sacc[4];
    int wib  = threadIdx.x >> 6;
    int lane = threadIdx.x & 63;
    int node = blockIdx.x * 4 + wib;
    float e = 0.0f;
    if (node < N_NODES) {
        float x = feats[(size_t)node * HDIM + lane];
        float h1 = ro_b1[lane];
        #pragma unroll 8
        for (int k = 0; k < HDIM; ++k) h1 += bcastf(x, k) * ro_w1[k * HDIM + lane];
        h1 = siluf(h1);
        int j = lane & 31;
        float h2 = ro_b2[j];
        #pragma unroll 8
        for (int k = 0; k < HDIM; ++k) h2 += bcastf(h1, k) * ro_w2[k * 32 + j];
        h2 = siluf(h2);
        float contrib = (lane < 32) ? h2 * ro_w3[j] : 0.0f;
        contrib = waveRedSum(contrib);
        e = contrib + ro_b3[0] + atomic_e[an[node]];
    }
    if (lane == 0) sacc[wib] = e;
    __syncthreads();
    if (threadIdx.x == 0)
        blockpart[blockIdx.x] = sacc[0] + sacc[1] + sacc[2] + sacc[3];
}

__global__ void k_final(const float* __restrict__ blockpart, int nb, float* __restrict__ out) {
    __shared__ float s[256];
    float acc = 0.f;
    for (int i = threadIdx.x; i < nb; i += 256) acc += blockpart[i];
    s[threadIdx.x] = acc; __syncthreads();
    for (int off = 128; off > 0; off >>= 1) {
        if (threadIdx.x < off) s[threadIdx.x] += s[threadIdx.x + off];
        __syncthreads();
    }
    if (threadIdx.x == 0) out[0] = s[0];
}

// ---------------- launch ----------------

extern "C" void kernel_launch(void* const* d_in, const int* in_sizes, int n_in,
                              void* d_out, int out_size, void* d_ws, size_t ws_size,
                              hipStream_t stream) {
    const int*   an       = (const int*)  d_in[0];
    const float* pos      = (const float*)d_in[1];
    const int*   edge     = (const int*)  d_in[2];
    const float* widths   = (const float*)d_in[3];
    const float* embed    = (const float*)d_in[4];
    const float* rad_w1   = (const float*)d_in[5];
    const float* rad_b1   = (const float*)d_in[6];
    const float* rad_w2   = (const float*)d_in[7];
    const float* rad_b2   = (const float*)d_in[8];
    const float* self_w   = (const float*)d_in[9];
    const float* self_b   = (const float*)d_in[10];
    const float* proj_w   = (const float*)d_in[11];
    const float* proj_b   = (const float*)d_in[12];
    const float* mlp_w1   = (const float*)d_in[13];
    const float* mlp_b1   = (const float*)d_in[14];
    const float* mlp_w2   = (const float*)d_in[15];
    const float* mlp_b2   = (const float*)d_in[16];
    const float* ln_g     = (const float*)d_in[17];
    const float* ln_b     = (const float*)d_in[18];
    const float* ro_w1    = (const float*)d_in[19];
    const float* ro_b1    = (const float*)d_in[20];
    const float* ro_w2    = (const float*)d_in[21];
    const float* ro_b2    = (const float*)d_in[22];
    const float* ro_w3    = (const float*)d_in[23];
    const float* ro_b3    = (const float*)d_in[24];
    const float* atomic_e = (const float*)d_in[25];

    char* w = (char*)d_ws;
    auto alloc = [&](size_t bytes) { char* p = w; w += (bytes + 255) & ~(size_t)255; return p; };
    float* feats     = (float*)alloc(sizeof(float) * N_NODES * HDIM);
    float* aggb      = (float*)alloc(sizeof(float) * N_NODES * HDIM);
    float* lut       = (float*)alloc(sizeof(float) * NLAYER * TLUT * HDIM);
    float* W2s       = (float*)alloc(sizeof(float) * NLAYER * HDIM * HDIM);
    float* b2s       = (float*)alloc(sizeof(float) * NLAYER * HDIM);
    float* Wsp       = (float*)alloc(sizeof(float) * NLAYER * HDIM * HDIM);
    float* bsp       = (float*)alloc(sizeof(float) * NLAYER * HDIM);
    int*   col_perm  = (int*)  alloc(sizeof(int) * N_EDGES);
    float* tpos_perm = (float*)alloc(sizeof(float) * N_EDGES);
    int*   starts    = (int*)  alloc(sizeof(int) * (N_NODES + 1));
    int*   cursor    = (int*)  alloc(sizeof(int) * N_NODES);
    int*   counts    = (int*)  alloc(sizeof(int) * N_NODES);
    int*   partial   = (int*)  alloc(sizeof(int) * 256);
    float* blockpart = (float*)alloc(sizeof(float) * 12500);
    (void)ws_size; (void)in_sizes; (void)n_in; (void)out_size;

    const int* erow = edge;
    const int* ecol = edge + N_EDGES;

    hipMemsetAsync(counts, 0, sizeof(int) * N_NODES, stream);
    k_embed<<<12500, 256, 0, stream>>>(an, embed, feats);
    k_hist<<<6250, 256, 0, stream>>>(erow, counts);
    k_scan1<<<196, 256, 0, stream>>>(counts, partial);
    k_scan2<<<1, 64, 0, stream>>>(partial, 196);
    k_scan3<<<196, 256, 0, stream>>>(counts, partial, starts, cursor);
    k_scatter<<<6250, 256, 0, stream>>>(erow, ecol, pos, cursor, col_perm, tpos_perm);
    k_w2s<<<80, 256, 0, stream>>>(rad_w2, W2s);
    k_wsp<<<80, 256, 0, stream>>>(self_w, proj_w, Wsp);
    k_bias<<<5, 64, 0, stream>>>(rad_b2, self_b, proj_w, proj_b, b2s, bsp);
    k_lut<<<NLAYER * TLUT, 64, 0, stream>>>(widths, rad_w1, rad_b1, W2s, b2s, lut);

    for (int l = 0; l < NLAYER; ++l) {
        k_agg<<<12500, 256, 0, stream>>>(feats, lut + (size_t)l * TLUT * HDIM,
                                         starts, col_perm, tpos_perm, aggb);
        k_node<<<1563, 256, 0, stream>>>(feats, aggb,
            Wsp + (size_t)l * HDIM * HDIM, bsp + l * HDIM,
            proj_w + (size_t)l * 2 * HDIM * HDIM,
            mlp_w1 + (size_t)l * HDIM * 2 * HDIM, mlp_b1 + l * 2 * HDIM,
            mlp_w2 + (size_t)l * 2 * HDIM * HDIM, mlp_b2 + l * HDIM,
            ln_g + l * HDIM, ln_b + l * HDIM);
    }

    k_readout<<<12500, 256, 0, stream>>>(feats, an, ro_w1, ro_b1, ro_w2, ro_b2,
                                         ro_w3, ro_b3, atomic_e, blockpart);
    k_final<<<1, 256, 0, stream>>>(blockpart, 12500, (float*)d_out);
}

// Round 2
// 1209.164 us; speedup vs baseline: 1.3477x; 1.3477x over previous
//
#include <hip/hip_runtime.h>
#include <math.h>

// Problem constants (from reference)
constexpr int N_NODES = 50000;
constexpr int N_EDGES = 1600000;
constexpr int HDIM    = 64;
constexpr int NLAYER  = 5;
constexpr int NBASIS  = 8;
constexpr int TLUT    = 512;           // radial LUT entries per layer
constexpr float CUT_R = 5.0f;
constexpr float PI_F  = 3.14159265358979f;

__device__ __forceinline__ float bcastf(float v, int l) {
    return __uint_as_float(__builtin_amdgcn_readlane(__float_as_uint(v), l));
}
__device__ __forceinline__ float waveRedSum(float v) {
    for (int off = 32; off > 0; off >>= 1) v += __shfl_xor(v, off, 64);
    return v;
}
__device__ __forceinline__ float siluf(float x) { return x / (1.0f + __expf(-x)); }

// ---------------- setup kernels ----------------

__global__ void k_embed(const int* __restrict__ an, const float* __restrict__ embed,
                        float* __restrict__ feats) {
    int i = blockIdx.x * blockDim.x + threadIdx.x;           // N*H threads
    if (i >= N_NODES * HDIM) return;
    int node = i >> 6, h = i & 63;
    feats[i] = embed[an[node] * HDIM + h];
}

__global__ void k_hist(const int* __restrict__ row, int* __restrict__ counts) {
    int e = blockIdx.x * blockDim.x + threadIdx.x;
    if (e < N_EDGES) atomicAdd(&counts[row[e]], 1);
}

__global__ void k_scan1(const int* __restrict__ counts, int* __restrict__ partial) {
    __shared__ int s[256];
    int i = blockIdx.x * 256 + threadIdx.x;
    int v = (i < N_NODES) ? counts[i] : 0;
    s[threadIdx.x] = v; __syncthreads();
    for (int off = 128; off > 0; off >>= 1) {
        if (threadIdx.x < off) s[threadIdx.x] += s[threadIdx.x + off];
        __syncthreads();
    }
    if (threadIdx.x == 0) partial[blockIdx.x] = s[0];
}

// single-block exclusive scan of block partials (nb <= 256)
__global__ void k_scan2(int* __restrict__ partial, int nb) {
    __shared__ int s[256];
    int v = (threadIdx.x < nb) ? partial[threadIdx.x] : 0;
    s[threadIdx.x] = v; __syncthreads();
    for (int off = 1; off < 256; off <<= 1) {
        int add = (threadIdx.x >= off) ? s[threadIdx.x - off] : 0;
        __syncthreads();
        s[threadIdx.x] += add;
        __syncthreads();
    }
    if (threadIdx.x < nb) partial[threadIdx.x] = s[threadIdx.x] - v;  // exclusive
}

__global__ void k_scan3(const int* __restrict__ counts, const int* __restrict__ partial,
                        int* __restrict__ starts, int* __restrict__ cursor) {
    __shared__ int s[256];
    int i = blockIdx.x * 256 + threadIdx.x;
    int v = (i < N_NODES) ? counts[i] : 0;
    s[threadIdx.x] = v; __syncthreads();
    for (int off = 1; off < 256; off <<= 1) {               // inclusive Hillis-Steele
        int add = (threadIdx.x >= off) ? s[threadIdx.x - off] : 0;
        __syncthreads();
        s[threadIdx.x] += add;
        __syncthreads();
    }
    if (i < N_NODES) {
        int st = partial[blockIdx.x] + s[threadIdx.x] - v;  // exclusive
        starts[i] = st; cursor[i] = st;
    }
    if (i == 0) starts[N_NODES] = N_EDGES;
}

// scatter edges into CSR order, packing (col, t) into 8B records
__global__ void k_scatter(const int* __restrict__ row, const int* __restrict__ col,
                          const float* __restrict__ pos, int* __restrict__ cursor,
                          int2* __restrict__ erec) {
    int e = blockIdx.x * blockDim.x + threadIdx.x;
    if (e >= N_EDGES) return;
    int r = row[e], c = col[e];
    int p = atomicAdd(&cursor[r], 1);
    float dx = pos[c * 3 + 0] - pos[r * 3 + 0];
    float dy = pos[c * 3 + 1] - pos[r * 3 + 1];
    float dz = pos[c * 3 + 2] - pos[r * 3 + 2];
    float len = sqrtf(dx * dx + dy * dy + dz * dz);
    float t = len * ((float)(TLUT - 1) / CUT_R);
    t = fminf(t, (float)(TLUT - 1));        // exact for len>=cutoff (rbf==0 there)
    erec[p] = make_int2(c, __float_as_int(t));
}

// W2s[l][k][h] = sum_{m<3} rad_w2[l][k][h*3+m]; Wsp[l][k][h] = (self_w @ proj_top)[k][h]
__global__ void k_prep(const float* __restrict__ rad_w2, const float* __restrict__ self_w,
                       const float* __restrict__ proj_w,
                       float* __restrict__ W2s, float* __restrict__ Wsp) {
    int i = blockIdx.x * blockDim.x + threadIdx.x;          // L*H*H
    if (i >= NLAYER * HDIM * HDIM) return;
    int l = i / (HDIM * HDIM); int rem = i % (HDIM * HDIM);
    int k = rem / HDIM; int h = rem % HDIM;
    const float* w = rad_w2 + ((size_t)l * HDIM + k) * (HDIM * 3) + h * 3;
    W2s[i] = w[0] + w[1] + w[2];
    const float* sw = self_w + ((size_t)l * HDIM + k) * HDIM;
    const float* pw = proj_w + (size_t)l * 2 * HDIM * HDIM;
    float acc = 0.f;
    for (int m = 0; m < HDIM; ++m) acc += sw[m] * pw[m * HDIM + h];
    Wsp[i] = acc;
}

// b2s[l][h] = sum_m rad_b2[l][h*3+m];  bsp[l][h] = self_b@proj_top + proj_b
__global__ void k_bias(const float* __restrict__ rad_b2, const float* __restrict__ self_b,
                       const float* __restrict__ proj_w, const float* __restrict__ proj_b,
                       float* __restrict__ b2s, float* __restrict__ bsp) {
    int i = blockIdx.x * blockDim.x + threadIdx.x;          // L*H
    if (i >= NLAYER * HDIM) return;
    int l = i / HDIM, h = i % HDIM;
    const float* rb2 = rad_b2 + l * HDIM * 3 + h * 3;
    b2s[i] = rb2[0] + rb2[1] + rb2[2];
    float acc = proj_b[l * HDIM + h];
    const float* pw = proj_w + (size_t)l * 2 * HDIM * HDIM;
    const float* sb = self_b + l * HDIM;
    for (int m = 0; m < HDIM; ++m) acc += sb[m] * pw[m * HDIM + h];
    bsp[i] = acc;
}

// radial LUT: lut[l][t][h] = (silu(rbf(len_t)@W1 + b1) @ W2s + b2s)[h]
__global__ void k_lut(const float* __restrict__ widths, const float* __restrict__ rad_w1,
                      const float* __restrict__ rad_b1, const float* __restrict__ W2s,
                      const float* __restrict__ b2s, float* __restrict__ lut) {
    int bid = blockIdx.x;                 // l*TLUT + t
    int l = bid / TLUT, t = bid % TLUT;
    int h = threadIdx.x;                  // 64 threads
    __shared__ float h1s[HDIM];
    float len = (float)t * (CUT_R / (float)(TLUT - 1));
    float cut = 0.0f;
    if (len < CUT_R) cut = 0.5f * (cosf(len * (PI_F / CUT_R)) + 1.0f);
    float acc = rad_b1[l * HDIM + h];
    for (int b = 0; b < NBASIS; ++b) {
        float wb = fmaxf(widths[b], 0.1f);
        float center = (float)b * (CUT_R / (float)(NBASIS - 1));
        float d = (len - center) / wb;
        float rbf = __expf(-0.5f * d * d) * cut;
        acc += rbf * rad_w1[(l * NBASIS + b) * HDIM + h];
    }
    h1s[h] = siluf(acc);
    __syncthreads();
    float o = b2s[l * HDIM + h];
    const float* w2 = W2s + (size_t)l * HDIM * HDIM;
    for (int k = 0; k < HDIM; ++k) o += h1s[k] * w2[k * HDIM + h];
    lut[(size_t)bid * HDIM + h] = o;
}

// pair adjacent LUT rows: lutP[l][t][j] = {lut[t][2j],lut[t][2j+1],lut[t1][2j],lut[t1][2j+1]}
__global__ void k_lutpair(const float* __restrict__ lut, float4* __restrict__ lutP) {
    int i = blockIdx.x * blockDim.x + threadIdx.x;          // L*TLUT*32
    if (i >= NLAYER * TLUT * 32) return;
    int j = i & 31;
    int lt = i >> 5;                       // l*TLUT + t
    int l = lt / TLUT, t = lt % TLUT;
    int t1 = (t < TLUT - 1) ? t + 1 : t;
    const float* r0 = lut + ((size_t)(l * TLUT + t)  * HDIM);
    const float* r1 = lut + ((size_t)(l * TLUT + t1) * HDIM);
    lutP[i] = make_float4(r0[2 * j], r0[2 * j + 1], r1[2 * j], r1[2 * j + 1]);
}

// ---------------- per-layer kernels ----------------

// one wave per node, 2 edge slots x 32 lanes (2 channels each):
// agg[i][h] = sum_{e in CSR(i)} feats[col[e]][h] * LUT(len_e)[h]
__global__ __launch_bounds__(256) void k_agg(const float2* __restrict__ feats2,
                                             const float4* __restrict__ lutP_l,
                                             const int* __restrict__ starts,
                                             const int2* __restrict__ erec,
                                             float2* __restrict__ agg2) {
    int wid  = (blockIdx.x * blockDim.x + threadIdx.x) >> 6;
    int lane = threadIdx.x & 63;
    int slot = lane >> 5;
    int j    = lane & 31;
    if (wid >= N_NODES) return;
    int e0 = starts[wid], e1 = starts[wid + 1];
    float ax = 0.f, ay = 0.f;
    #pragma unroll 2
    for (int e = e0 + slot; e < e1; e += 2) {
        int2  r = erec[e];
        int   c = r.x;
        float t = __int_as_float(r.y);
        int   i0 = (int)t;
        float f  = t - (float)i0;
        float4 w  = lutP_l[i0 * 32 + j];
        float2 fv = feats2[(size_t)c * 32 + j];
        float wv0 = w.x + f * (w.z - w.x);
        float wv1 = w.y + f * (w.w - w.y);
        ax += fv.x * wv0;
        ay += fv.y * wv1;
    }
    ax += __shfl_xor(ax, 32, 64);
    ay += __shfl_xor(ay, 32, 64);
    if (slot == 0) agg2[(size_t)wid * 32 + j] = make_float2(ax, ay);
}

// one wave per 8 nodes: conv -> mlp -> residual+LN, weights broadcast via readlane
constexpr int NT = 8;
__global__ __launch_bounds__(256) void k_node(float* __restrict__ feats,
        const float* __restrict__ agg,
        const float* __restrict__ Wsp_l, const float* __restrict__ bsp_l,
        const float* __restrict__ projw_l,
        const float* __restrict__ mlp_w1_l, const float* __restrict__ mlp_b1_l,
        const float* __restrict__ mlp_w2_l, const float* __restrict__ mlp_b2_l,
        const float* __restrict__ ln_g_l, const float* __restrict__ ln_b_l) {
    int wid  = (blockIdx.x * blockDim.x + threadIdx.x) >> 6;
    int lane = threadIdx.x & 63;
    int base = wid * NT;
    if (base >= N_NODES) return;
    const float* pb = projw_l + HDIM * HDIM;   // bottom half of proj_w

    float x[NT], a[NT];
    #pragma unroll
    for (int n = 0; n < NT; ++n) {
        int node = base + n;
        if (node < N_NODES) {
            x[n] = feats[(size_t)node * HDIM + lane];
            a[n] = agg[(size_t)node * HDIM + lane];
        } else { x[n] = 0.f; a[n] = 0.f; }
    }

    float conv[NT];
    float bspv = bsp_l[lane];
    #pragma unroll
    for (int n = 0; n < NT; ++n) conv[n] = bspv;
    #pragma unroll 8
    for (int k = 0; k < HDIM; ++k) {
        float wk = Wsp_l[k * HDIM + lane];
        float pk = pb[k * HDIM + lane];
        #pragma unroll
        for (int n = 0; n < NT; ++n) {
            conv[n] += bcastf(x[n], k) * wk + bcastf(a[n], k) * pk;
        }
    }

    float m1a[NT], m1b[NT];
    {
        float b1a = mlp_b1_l[lane], b1b = mlp_b1_l[HDIM + lane];
        #pragma unroll
        for (int n = 0; n < NT; ++n) { m1a[n] = b1a; m1b[n] = b1b; }
    }
    #pragma unroll 8
    for (int k = 0; k < HDIM; ++k) {
        float w1a = mlp_w1_l[k * 2 * HDIM + lane];
        float w1b = mlp_w1_l[k * 2 * HDIM + HDIM + lane];
        #pragma unroll
        for (int n = 0; n < NT; ++n) {
            float ck = bcastf(conv[n], k);
            m1a[n] += ck * w1a;
            m1b[n] += ck * w1b;
        }
    }
    #pragma unroll
    for (int n = 0; n < NT; ++n) { m1a[n] = siluf(m1a[n]); m1b[n] = siluf(m1b[n]); }

    float upd[NT];
    {
        float b2v = mlp_b2_l[lane];
        #pragma unroll
        for (int n = 0; n < NT; ++n) upd[n] = b2v;
    }
    #pragma unroll 8
    for (int j = 0; j < HDIM; ++j) {
        float w2a = mlp_w2_l[j * HDIM + lane];
        float w2b = mlp_w2_l[(HDIM + j) * HDIM + lane];
        #pragma unroll
        for (int n = 0; n < NT; ++n) {
            upd[n] += bcastf(m1a[n], j) * w2a + bcastf(m1b[n], j) * w2b;
        }
    }

    float gv = ln_g_l[lane], bv = ln_b_l[lane];
    #pragma unroll
    for (int n = 0; n < NT; ++n) {
        float y  = x[n] + upd[n];
        float s1 = waveRedSum(y);
        float s2 = waveRedSum(y * y);
        float mu  = s1 * (1.0f / HDIM);
        float var = s2 * (1.0f / HDIM) - mu * mu;
        float r = rsqrtf(var + 1e-5f);
        int node = base + n;
        if (node < N_NODES)
            feats[(size_t)node * HDIM + lane] = (y - mu) * r * gv + bv;
    }
}

// ---------------- readout ----------------

__global__ __launch_bounds__(256) void k_readout(const float* __restrict__ feats,
        const int* __restrict__ an,
        const float* __restrict__ ro_w1, const float* __restrict__ ro_b1,
        const float* __restrict__ ro_w2, const float* __restrict__ ro_b2,
        const float* __restrict__ ro_w3, const float* __restrict__ ro_b3,
        const float* __restrict__ atomic_e, float* __restrict__ blockpart) {
    __shared__ float sacc[4];
    int wib  = threadIdx.x >> 6;
    int lane = threadIdx.x & 63;
    int node = blockIdx.x * 4 + wib;
    float e = 0.0f;
    if (node < N_NODES) {
        float x = feats[(size_t)node * HDIM + lane];
        float h1 = ro_b1[lane];
        #pragma unroll 8
        for (int k = 0; k < HDIM; ++k) h1 += bcastf(x, k) * ro_w1[k * HDIM + lane];
        h1 = siluf(h1);
        int j = lane & 31;
        float h2 = ro_b2[j];
        #pragma unroll 8
        for (int k = 0; k < HDIM; ++k) h2 += bcastf(h1, k) * ro_w2[k * 32 + j];
        h2 = siluf(h2);
        float contrib = (lane < 32) ? h2 * ro_w3[j] : 0.0f;
        contrib = waveRedSum(contrib);
        e = contrib + ro_b3[0] + atomic_e[an[node]];
    }
    if (lane == 0) sacc[wib] = e;
    __syncthreads();
    if (threadIdx.x == 0)
        blockpart[blockIdx.x] = sacc[0] + sacc[1] + sacc[2] + sacc[3];
}

__global__ void k_final(const float* __restrict__ blockpart, int nb, float* __restrict__ out) {
    __shared__ float s[256];
    float acc = 0.f;
    for (int i = threadIdx.x; i < nb; i += 256) acc += blockpart[i];
    s[threadIdx.x] = acc; __syncthreads();
    for (int off = 128; off > 0; off >>= 1) {
        if (threadIdx.x < off) s[threadIdx.x] += s[threadIdx.x + off];
        __syncthreads();
    }
    if (threadIdx.x == 0) out[0] = s[0];
}

// ---------------- launch ----------------

extern "C" void kernel_launch(void* const* d_in, const int* in_sizes, int n_in,
                              void* d_out, int out_size, void* d_ws, size_t ws_size,
                              hipStream_t stream) {
    const int*   an       = (const int*)  d_in[0];
    const float* pos      = (const float*)d_in[1];
    const int*   edge     = (const int*)  d_in[2];
    const float* widths   = (const float*)d_in[3];
    const float* embed    = (const float*)d_in[4];
    const float* rad_w1   = (const float*)d_in[5];
    const float* rad_b1   = (const float*)d_in[6];
    const float* rad_w2   = (const float*)d_in[7];
    const float* rad_b2   = (const float*)d_in[8];
    const float* self_w   = (const float*)d_in[9];
    const float* self_b   = (const float*)d_in[10];
    const float* proj_w   = (const float*)d_in[11];
    const float* proj_b   = (const float*)d_in[12];
    const float* mlp_w1   = (const float*)d_in[13];
    const float* mlp_b1   = (const float*)d_in[14];
    const float* mlp_w2   = (const float*)d_in[15];
    const float* mlp_b2   = (const float*)d_in[16];
    const float* ln_g     = (const float*)d_in[17];
    const float* ln_b     = (const float*)d_in[18];
    const float* ro_w1    = (const float*)d_in[19];
    const float* ro_b1    = (const float*)d_in[20];
    const float* ro_w2    = (const float*)d_in[21];
    const float* ro_b2    = (const float*)d_in[22];
    const float* ro_w3    = (const float*)d_in[23];
    const float* ro_b3    = (const float*)d_in[24];
    const float* atomic_e = (const float*)d_in[25];

    char* w = (char*)d_ws;
    auto alloc = [&](size_t bytes) { char* p = w; w += (bytes + 255) & ~(size_t)255; return p; };
    float* feats     = (float*)alloc(sizeof(float) * N_NODES * HDIM);
    float* aggb      = (float*)alloc(sizeof(float) * N_NODES * HDIM);
    float* lut       = (float*)alloc(sizeof(float) * NLAYER * TLUT * HDIM);
    float4* lutP     = (float4*)alloc(sizeof(float4) * NLAYER * TLUT * 32);
    float* W2s       = (float*)alloc(sizeof(float) * NLAYER * HDIM * HDIM);
    float* b2s       = (float*)alloc(sizeof(float) * NLAYER * HDIM);
    float* Wsp       = (float*)alloc(sizeof(float) * NLAYER * HDIM * HDIM);
    float* bsp       = (float*)alloc(sizeof(float) * NLAYER * HDIM);
    int2*  erec      = (int2*) alloc(sizeof(int2) * N_EDGES);
    int*   starts    = (int*)  alloc(sizeof(int) * (N_NODES + 1));
    int*   cursor    = (int*)  alloc(sizeof(int) * N_NODES);
    int*   counts    = (int*)  alloc(sizeof(int) * N_NODES);
    int*   partial   = (int*)  alloc(sizeof(int) * 256);
    float* blockpart = (float*)alloc(sizeof(float) * 12500);
    (void)ws_size; (void)in_sizes; (void)n_in; (void)out_size;

    const int* erow = edge;
    const int* ecol = edge + N_EDGES;

    hipMemsetAsync(counts, 0, sizeof(int) * N_NODES, stream);
    k_embed<<<12500, 256, 0, stream>>>(an, embed, feats);
    k_hist<<<6250, 256, 0, stream>>>(erow, counts);
    k_scan1<<<196, 256, 0, stream>>>(counts, partial);
    k_scan2<<<1, 256, 0, stream>>>(partial, 196);
    k_scan3<<<196, 256, 0, stream>>>(counts, partial, starts, cursor);
    k_scatter<<<6250, 256, 0, stream>>>(erow, ecol, pos, cursor, erec);
    k_prep<<<80, 256, 0, stream>>>(rad_w2, self_w, proj_w, W2s, Wsp);
    k_bias<<<5, 64, 0, stream>>>(rad_b2, self_b, proj_w, proj_b, b2s, bsp);
    k_lut<<<NLAYER * TLUT, 64, 0, stream>>>(widths, rad_w1, rad_b1, W2s, b2s, lut);
    k_lutpair<<<(NLAYER * TLUT * 32 + 255) / 256, 256, 0, stream>>>(lut, lutP);

    for (int l = 0; l < NLAYER; ++l) {
        k_agg<<<12500, 256, 0, stream>>>((const float2*)feats,
                                         lutP + (size_t)l * TLUT * 32,
                                         starts, erec, (float2*)aggb);
        k_node<<<1563, 256, 0, stream>>>(feats, aggb,
            Wsp + (size_t)l * HDIM * HDIM, bsp + l * HDIM,
            proj_w + (size_t)l * 2 * HDIM * HDIM,
            mlp_w1 + (size_t)l * HDIM * 2 * HDIM, mlp_b1 + l * 2 * HDIM,
            mlp_w2 + (size_t)l * 2 * HDIM * HDIM, mlp_b2 + l * HDIM,
            ln_g + l * HDIM, ln_b + l * HDIM);
    }

    k_readout<<<12500, 256, 0, stream>>>(feats, an, ro_w1, ro_b1, ro_w2, ro_b2,
                                         ro_w3, ro_b3, atomic_e, blockpart);
    k_final<<<1, 256, 0, stream>>>(blockpart, 12500, (float*)d_out);
}

// Round 3
// 1135.195 us; speedup vs baseline: 1.4355x; 1.0652x over previous
//
#include <hip/hip_runtime.h>
#include <math.h>

// Problem constants (from reference)
constexpr int N_NODES = 50000;
constexpr int N_EDGES = 1600000;
constexpr int HDIM    = 64;
constexpr int NLAYER  = 5;
constexpr int NBASIS  = 8;
constexpr int TLUT    = 512;           // radial LUT entries per layer
constexpr float CUT_R = 5.0f;
constexpr float PI_F  = 3.14159265358979f;

__device__ __forceinline__ float bcastf(float v, int l) {
    return __uint_as_float(__builtin_amdgcn_readlane(__float_as_uint(v), l));
}
__device__ __forceinline__ float waveRedSum(float v) {
    for (int off = 32; off > 0; off >>= 1) v += __shfl_xor(v, off, 64);
    return v;
}
__device__ __forceinline__ float siluf(float x) { return x / (1.0f + __expf(-x)); }

// ---------------- setup kernels ----------------

__global__ void k_embed(const int* __restrict__ an, const float* __restrict__ embed,
                        float* __restrict__ feats) {
    int i = blockIdx.x * blockDim.x + threadIdx.x;           // N*H threads
    if (i >= N_NODES * HDIM) return;
    int node = i >> 6, h = i & 63;
    feats[i] = embed[an[node] * HDIM + h];
}

__global__ void k_hist(const int* __restrict__ row, int* __restrict__ counts) {
    int e = blockIdx.x * blockDim.x + threadIdx.x;
    if (e < N_EDGES) atomicAdd(&counts[row[e]], 1);
}

__global__ void k_scan1(const int* __restrict__ counts, int* __restrict__ partial) {
    __shared__ int s[256];
    int i = blockIdx.x * 256 + threadIdx.x;
    int v = (i < N_NODES) ? counts[i] : 0;
    s[threadIdx.x] = v; __syncthreads();
    for (int off = 128; off > 0; off >>= 1) {
        if (threadIdx.x < off) s[threadIdx.x] += s[threadIdx.x + off];
        __syncthreads();
    }
    if (threadIdx.x == 0) partial[blockIdx.x] = s[0];
}

// single-block exclusive scan of block partials (nb <= 256)
__global__ void k_scan2(int* __restrict__ partial, int nb) {
    __shared__ int s[256];
    int v = (threadIdx.x < nb) ? partial[threadIdx.x] : 0;
    s[threadIdx.x] = v; __syncthreads();
    for (int off = 1; off < 256; off <<= 1) {
        int add = (threadIdx.x >= off) ? s[threadIdx.x - off] : 0;
        __syncthreads();
        s[threadIdx.x] += add;
        __syncthreads();
    }
    if (threadIdx.x < nb) partial[threadIdx.x] = s[threadIdx.x] - v;  // exclusive
}

__global__ void k_scan3(const int* __restrict__ counts, const int* __restrict__ partial,
                        int* __restrict__ starts, int* __restrict__ cursor) {
    __shared__ int s[256];
    int i = blockIdx.x * 256 + threadIdx.x;
    int v = (i < N_NODES) ? counts[i] : 0;
    s[threadIdx.x] = v; __syncthreads();
    for (int off = 1; off < 256; off <<= 1) {               // inclusive Hillis-Steele
        int add = (threadIdx.x >= off) ? s[threadIdx.x - off] : 0;
        __syncthreads();
        s[threadIdx.x] += add;
        __syncthreads();
    }
    if (i < N_NODES) {
        int st = partial[blockIdx.x] + s[threadIdx.x] - v;  // exclusive
        starts[i] = st; cursor[i] = st;
    }
    if (i == 0) starts[N_NODES] = N_EDGES;
}

// scatter edges into CSR order, packing (col, t) into 8B records
__global__ void k_scatter(const int* __restrict__ row, const int* __restrict__ col,
                          const float* __restrict__ pos, int* __restrict__ cursor,
                          int2* __restrict__ erec) {
    int e = blockIdx.x * blockDim.x + threadIdx.x;
    if (e >= N_EDGES) return;
    int r = row[e], c = col[e];
    int p = atomicAdd(&cursor[r], 1);
    float dx = pos[c * 3 + 0] - pos[r * 3 + 0];
    float dy = pos[c * 3 + 1] - pos[r * 3 + 1];
    float dz = pos[c * 3 + 2] - pos[r * 3 + 2];
    float len = sqrtf(dx * dx + dy * dy + dz * dz);
    float t = len * ((float)(TLUT - 1) / CUT_R);
    t = fminf(t, (float)(TLUT - 1));        // exact for len>=cutoff (rbf==0 there)
    erec[p] = make_int2(c, __float_as_int(t));
}

// W2s[l][k][h] = sum_{m<3} rad_w2[l][k][h*3+m]; Wsp[l][k][h] = (self_w @ proj_top)[k][h]
__global__ void k_prep(const float* __restrict__ rad_w2, const float* __restrict__ self_w,
                       const float* __restrict__ proj_w,
                       float* __restrict__ W2s, float* __restrict__ Wsp) {
    int i = blockIdx.x * blockDim.x + threadIdx.x;          // L*H*H
    if (i >= NLAYER * HDIM * HDIM) return;
    int l = i / (HDIM * HDIM); int rem = i % (HDIM * HDIM);
    int k = rem / HDIM; int h = rem % HDIM;
    const float* w = rad_w2 + ((size_t)l * HDIM + k) * (HDIM * 3) + h * 3;
    W2s[i] = w[0] + w[1] + w[2];
    const float* sw = self_w + ((size_t)l * HDIM + k) * HDIM;
    const float* pw = proj_w + (size_t)l * 2 * HDIM * HDIM;
    float acc = 0.f;
    for (int m = 0; m < HDIM; ++m) acc += sw[m] * pw[m * HDIM + h];
    Wsp[i] = acc;
}

// b2s[l][h] = sum_m rad_b2[l][h*3+m];  bsp[l][h] = self_b@proj_top + proj_b
__global__ void k_bias(const float* __restrict__ rad_b2, const float* __restrict__ self_b,
                       const float* __restrict__ proj_w, const float* __restrict__ proj_b,
                       float* __restrict__ b2s, float* __restrict__ bsp) {
    int i = blockIdx.x * blockDim.x + threadIdx.x;          // L*H
    if (i >= NLAYER * HDIM) return;
    int l = i / HDIM, h = i % HDIM;
    const float* rb2 = rad_b2 + l * HDIM * 3 + h * 3;
    b2s[i] = rb2[0] + rb2[1] + rb2[2];
    float acc = proj_b[l * HDIM + h];
    const float* pw = proj_w + (size_t)l * 2 * HDIM * HDIM;
    const float* sb = self_b + l * HDIM;
    for (int m = 0; m < HDIM; ++m) acc += sb[m] * pw[m * HDIM + h];
    bsp[i] = acc;
}

// radial LUT: lut[l][t][h] = (silu(rbf(len_t)@W1 + b1) @ W2s + b2s)[h]
__global__ void k_lut(const float* __restrict__ widths, const float* __restrict__ rad_w1,
                      const float* __restrict__ rad_b1, const float* __restrict__ W2s,
                      const float* __restrict__ b2s, float* __restrict__ lut) {
    int bid = blockIdx.x;                 // l*TLUT + t
    int l = bid / TLUT, t = bid % TLUT;
    int h = threadIdx.x;                  // 64 threads
    __shared__ float h1s[HDIM];
    float len = (float)t * (CUT_R / (float)(TLUT - 1));
    float cut = 0.0f;
    if (len < CUT_R) cut = 0.5f * (cosf(len * (PI_F / CUT_R)) + 1.0f);
    float acc = rad_b1[l * HDIM + h];
    for (int b = 0; b < NBASIS; ++b) {
        float wb = fmaxf(widths[b], 0.1f);
        float center = (float)b * (CUT_R / (float)(NBASIS - 1));
        float d = (len - center) / wb;
        float rbf = __expf(-0.5f * d * d) * cut;
        acc += rbf * rad_w1[(l * NBASIS + b) * HDIM + h];
    }
    h1s[h] = siluf(acc);
    __syncthreads();
    float o = b2s[l * HDIM + h];
    const float* w2 = W2s + (size_t)l * HDIM * HDIM;
    for (int k = 0; k < HDIM; ++k) o += h1s[k] * w2[k * HDIM + h];
    lut[(size_t)bid * HDIM + h] = o;
}

// lutQ[(l*TLUT+t)*16+j] = pair {row t ch 4j..4j+3, row t+1 ch 4j..4j+3}
__global__ void k_lutq(const float* __restrict__ lut, float4* __restrict__ lutQ) {
    int i = blockIdx.x * blockDim.x + threadIdx.x;          // L*TLUT*16
    if (i >= NLAYER * TLUT * 16) return;
    int j = i & 15;
    int lt = i >> 4;                       // l*TLUT + t
    int l = lt / TLUT, t = lt % TLUT;
    int t1 = (t < TLUT - 1) ? t + 1 : t;
    const float* r0 = lut + (size_t)(l * TLUT + t)  * HDIM + 4 * j;
    const float* r1 = lut + (size_t)(l * TLUT + t1) * HDIM + 4 * j;
    lutQ[(size_t)i * 2 + 0] = make_float4(r0[0], r0[1], r0[2], r0[3]);
    lutQ[(size_t)i * 2 + 1] = make_float4(r1[0], r1[1], r1[2], r1[3]);
}

// ---------------- per-layer kernels ----------------

// one wave per node, 4 edge slots x 16 lanes (4 channels each via float4)
__global__ __launch_bounds__(256) void k_agg(const float4* __restrict__ feats4,
                                             const float4* __restrict__ lutQ_l,
                                             const int* __restrict__ starts,
                                             const int2* __restrict__ erec,
                                             float4* __restrict__ agg4) {
    int wid  = (blockIdx.x * blockDim.x + threadIdx.x) >> 6;
    int lane = threadIdx.x & 63;
    int slot = lane >> 4;
    int j    = lane & 15;
    if (wid >= N_NODES) return;
    int e0 = starts[wid], e1 = starts[wid + 1];
    float ax = 0.f, ay = 0.f, az = 0.f, aw = 0.f;
    #pragma unroll 2
    for (int e = e0 + slot; e < e1; e += 4) {
        int2  r = erec[e];
        int   c = r.x;
        float t = __int_as_float(r.y);
        int   i0 = (int)t;
        float f  = t - (float)i0;
        const float4* q = lutQ_l + ((size_t)(i0 * 16 + j) * 2);
        float4 w0 = q[0];
        float4 w1 = q[1];
        float4 fv = feats4[(size_t)c * 16 + j];
        ax += fv.x * (w0.x + f * (w1.x - w0.x));
        ay += fv.y * (w0.y + f * (w1.y - w0.y));
        az += fv.z * (w0.z + f * (w1.z - w0.z));
        aw += fv.w * (w0.w + f * (w1.w - w0.w));
    }
    // reduce across the 4 slots (lanes j, j+16, j+32, j+48)
    ax += __shfl_xor(ax, 16, 64);  ay += __shfl_xor(ay, 16, 64);
    az += __shfl_xor(az, 16, 64);  aw += __shfl_xor(aw, 16, 64);
    ax += __shfl_xor(ax, 32, 64);  ay += __shfl_xor(ay, 32, 64);
    az += __shfl_xor(az, 32, 64);  aw += __shfl_xor(aw, 32, 64);
    if (slot == 0) agg4[(size_t)wid * 16 + j] = make_float4(ax, ay, az, aw);
}

// one wave per 64 nodes; lane = node. Weights stream through SGPRs (wave-uniform),
// per-node vectors live per-lane; dynamic-k reads go through LDS (pitch 65/129).
__global__ __launch_bounds__(64) void k_node(float* __restrict__ feats,
        const float* __restrict__ agg,
        const float* __restrict__ Wsp_l, const float* __restrict__ bsp_l,
        const float* __restrict__ projw_l,
        const float* __restrict__ mlp_w1_l, const float* __restrict__ mlp_b1_l,
        const float* __restrict__ mlp_w2_l, const float* __restrict__ mlp_b2_l,
        const float* __restrict__ ln_g_l, const float* __restrict__ ln_b_l) {
    __shared__ float lds[8320];            // A=[0,4160) x-tile, B=[4160,8320) a-tile; later m1 pitch 129
    const int lane = threadIdx.x;
    const int nb0  = blockIdx.x * 64;
    const float* pb = projw_l + HDIM * HDIM;   // bottom half of proj_w

    // stage x and a tiles (coalesced rows)
    #pragma unroll 8
    for (int r = 0; r < 64; ++r) {
        int nd  = nb0 + r;
        int nds = (nd < N_NODES) ? nd : (N_NODES - 1);
        lds[r * 65 + lane]        = feats[(size_t)nds * HDIM + lane];
        lds[4160 + r * 65 + lane] = agg[(size_t)nds * HDIM + lane];
    }
    __syncthreads();

    // conv = bsp + x@Wsp + a@Pb
    float conv_r[64];
    #pragma unroll
    for (int h = 0; h < 64; ++h) conv_r[h] = bsp_l[h];
    for (int k = 0; k < 64; ++k) {
        float xk = lds[lane * 65 + k];
        const float* wr = Wsp_l + k * 64;
        #pragma unroll
        for (int h = 0; h < 64; ++h) conv_r[h] = fmaf(xk, wr[h], conv_r[h]);
    }
    for (int k = 0; k < 64; ++k) {
        float ak = lds[4160 + lane * 65 + k];
        const float* wr = pb + k * 64;
        #pragma unroll
        for (int h = 0; h < 64; ++h) conv_r[h] = fmaf(ak, wr[h], conv_r[h]);
    }
    // keep x for the residual (static extract)
    float x_r[64];
    #pragma unroll
    for (int h = 0; h < 64; ++h) x_r[h] = lds[lane * 65 + h];
    __syncthreads();
    // dump conv into region A
    #pragma unroll
    for (int h = 0; h < 64; ++h) lds[lane * 65 + h] = conv_r[h];
    __syncthreads();

    // m1 = silu(conv @ W1 + b1), 128 wide
    float m1_r[128];
    #pragma unroll
    for (int j = 0; j < 128; ++j) m1_r[j] = mlp_b1_l[j];
    for (int k = 0; k < 64; ++k) {
        float ck = lds[lane * 65 + k];
        const float* wr = mlp_w1_l + k * 128;
        #pragma unroll
        for (int j = 0; j < 128; ++j) m1_r[j] = fmaf(ck, wr[j], m1_r[j]);
    }
    #pragma unroll
    for (int j = 0; j < 128; ++j) m1_r[j] = siluf(m1_r[j]);
    __syncthreads();
    // dump m1 (pitch 129 spans the whole lds array)
    #pragma unroll
    for (int j = 0; j < 128; ++j) lds[lane * 129 + j] = m1_r[j];
    __syncthreads();

    // upd = m1 @ W2 + b2
    float upd_r[64];
    #pragma unroll
    for (int h = 0; h < 64; ++h) upd_r[h] = mlp_b2_l[h];
    for (int k = 0; k < 128; ++k) {
        float mk = lds[lane * 129 + k];
        const float* wr = mlp_w2_l + k * 64;
        #pragma unroll
        for (int h = 0; h < 64; ++h) upd_r[h] = fmaf(mk, wr[h], upd_r[h]);
    }

    // residual + LayerNorm (fully per-lane)
    float s1 = 0.f, s2 = 0.f;
    #pragma unroll
    for (int h = 0; h < 64; ++h) {
        float y = x_r[h] + upd_r[h];
        x_r[h] = y;
        s1 += y; s2 += y * y;
    }
    float mu  = s1 * (1.0f / 64.0f);
    float var = s2 * (1.0f / 64.0f) - mu * mu;
    float rr  = rsqrtf(var + 1e-5f);
    __syncthreads();
    #pragma unroll
    for (int h = 0; h < 64; ++h)
        lds[lane * 65 + h] = (x_r[h] - mu) * rr * ln_g_l[h] + ln_b_l[h];
    __syncthreads();
    #pragma unroll 8
    for (int r = 0; r < 64; ++r) {
        int nd = nb0 + r;
        if (nd < N_NODES) feats[(size_t)nd * HDIM + lane] = lds[r * 65 + lane];
    }
}

// ---------------- readout ----------------

__global__ __launch_bounds__(256) void k_readout(const float* __restrict__ feats,
        const int* __restrict__ an,
        const float* __restrict__ ro_w1, const float* __restrict__ ro_b1,
        const float* __restrict__ ro_w2, const float* __restrict__ ro_b2,
        const float* __restrict__ ro_w3, const float* __restrict__ ro_b3,
        const float* __restrict__ atomic_e, float* __restrict__ blockpart) {
    __shared__ float sacc[4];
    int wib  = threadIdx.x >> 6;
    int lane = threadIdx.x & 63;
    int node = blockIdx.x * 4 + wib;
    float e = 0.0f;
    if (node < N_NODES) {
        float x = feats[(size_t)node * HDIM + lane];
        float h1 = ro_b1[lane];
        #pragma unroll 8
        for (int k = 0; k < HDIM; ++k) h1 += bcastf(x, k) * ro_w1[k * HDIM + lane];
        h1 = siluf(h1);
        int j = lane & 31;
        float h2 = ro_b2[j];
        #pragma unroll 8
        for (int k = 0; k < HDIM; ++k) h2 += bcastf(h1, k) * ro_w2[k * 32 + j];
        h2 = siluf(h2);
        float contrib = (lane < 32) ? h2 * ro_w3[j] : 0.0f;
        contrib = waveRedSum(contrib);
        e = contrib + ro_b3[0] + atomic_e[an[node]];
    }
    if (lane == 0) sacc[wib] = e;
    __syncthreads();
    if (threadIdx.x == 0)
        blockpart[blockIdx.x] = sacc[0] + sacc[1] + sacc[2] + sacc[3];
}

__global__ void k_final(const float* __restrict__ blockpart, int nb, float* __restrict__ out) {
    __shared__ float s[256];
    float acc = 0.f;
    for (int i = threadIdx.x; i < nb; i += 256) acc += blockpart[i];
    s[threadIdx.x] = acc; __syncthreads();
    for (int off = 128; off > 0; off >>= 1) {
        if (threadIdx.x < off) s[threadIdx.x] += s[threadIdx.x + off];
        __syncthreads();
    }
    if (threadIdx.x == 0) out[0] = s[0];
}

// ---------------- launch ----------------

extern "C" void kernel_launch(void* const* d_in, const int* in_sizes, int n_in,
                              void* d_out, int out_size, void* d_ws, size_t ws_size,
                              hipStream_t stream) {
    const int*   an       = (const int*)  d_in[0];
    const float* pos      = (const float*)d_in[1];
    const int*   edge     = (const int*)  d_in[2];
    const float* widths   = (const float*)d_in[3];
    const float* embed    = (const float*)d_in[4];
    const float* rad_w1   = (const float*)d_in[5];
    const float* rad_b1   = (const float*)d_in[6];
    const float* rad_w2   = (const float*)d_in[7];
    const float* rad_b2   = (const float*)d_in[8];
    const float* self_w   = (const float*)d_in[9];
    const float* self_b   = (const float*)d_in[10];
    const float* proj_w   = (const float*)d_in[11];
    const float* proj_b   = (const float*)d_in[12];
    const float* mlp_w1   = (const float*)d_in[13];
    const float* mlp_b1   = (const float*)d_in[14];
    const float* mlp_w2   = (const float*)d_in[15];
    const float* mlp_b2   = (const float*)d_in[16];
    const float* ln_g     = (const float*)d_in[17];
    const float* ln_b     = (const float*)d_in[18];
    const float* ro_w1    = (const float*)d_in[19];
    const float* ro_b1    = (const float*)d_in[20];
    const float* ro_w2    = (const float*)d_in[21];
    const float* ro_b2    = (const float*)d_in[22];
    const float* ro_w3    = (const float*)d_in[23];
    const float* ro_b3    = (const float*)d_in[24];
    const float* atomic_e = (const float*)d_in[25];

    char* w = (char*)d_ws;
    auto alloc = [&](size_t bytes) { char* p = w; w += (bytes + 255) & ~(size_t)255; return p; };
    float* feats     = (float*)alloc(sizeof(float) * N_NODES * HDIM);
    float* aggb      = (float*)alloc(sizeof(float) * N_NODES * HDIM);
    float* lut       = (float*)alloc(sizeof(float) * NLAYER * TLUT * HDIM);
    float4* lutQ     = (float4*)alloc(sizeof(float4) * NLAYER * TLUT * 32);
    float* W2s       = (float*)alloc(sizeof(float) * NLAYER * HDIM * HDIM);
    float* b2s       = (float*)alloc(sizeof(float) * NLAYER * HDIM);
    float* Wsp       = (float*)alloc(sizeof(float) * NLAYER * HDIM * HDIM);
    float* bsp       = (float*)alloc(sizeof(float) * NLAYER * HDIM);
    int2*  erec      = (int2*) alloc(sizeof(int2) * N_EDGES);
    int*   starts    = (int*)  alloc(sizeof(int) * (N_NODES + 1));
    int*   cursor    = (int*)  alloc(sizeof(int) * N_NODES);
    int*   counts    = (int*)  alloc(sizeof(int) * N_NODES);
    int*   partial   = (int*)  alloc(sizeof(int) * 256);
    float* blockpart = (float*)alloc(sizeof(float) * 12500);
    (void)ws_size; (void)in_sizes; (void)n_in; (void)out_size;

    const int* erow = edge;
    const int* ecol = edge + N_EDGES;

    hipMemsetAsync(counts, 0, sizeof(int) * N_NODES, stream);
    k_embed<<<12500, 256, 0, stream>>>(an, embed, feats);
    k_hist<<<6250, 256, 0, stream>>>(erow, counts);
    k_scan1<<<196, 256, 0, stream>>>(counts, partial);
    k_scan2<<<1, 256, 0, stream>>>(partial, 196);
    k_scan3<<<196, 256, 0, stream>>>(counts, partial, starts, cursor);
    k_scatter<<<6250, 256, 0, stream>>>(erow, ecol, pos, cursor, erec);
    k_prep<<<80, 256, 0, stream>>>(rad_w2, self_w, proj_w, W2s, Wsp);
    k_bias<<<5, 64, 0, stream>>>(rad_b2, self_b, proj_w, proj_b, b2s, bsp);
    k_lut<<<NLAYER * TLUT, 64, 0, stream>>>(widths, rad_w1, rad_b1, W2s, b2s, lut);
    k_lutq<<<(NLAYER * TLUT * 16 + 255) / 256, 256, 0, stream>>>(lut, lutQ);

    for (int l = 0; l < NLAYER; ++l) {
        k_agg<<<12500, 256, 0, stream>>>((const float4*)feats,
                                         lutQ + (size_t)l * TLUT * 32,
                                         starts, erec, (float4*)aggb);
        k_node<<<782, 64, 0, stream>>>(feats, aggb,
            Wsp + (size_t)l * HDIM * HDIM, bsp + l * HDIM,
            proj_w + (size_t)l * 2 * HDIM * HDIM,
            mlp_w1 + (size_t)l * HDIM * 2 * HDIM, mlp_b1 + l * 2 * HDIM,
            mlp_w2 + (size_t)l * 2 * HDIM * HDIM, mlp_b2 + l * HDIM,
            ln_g + l * HDIM, ln_b + l * HDIM);
    }

    k_readout<<<12500, 256, 0, stream>>>(feats, an, ro_w1, ro_b1, ro_w2, ro_b2,
                                         ro_w3, ro_b3, atomic_e, blockpart);
    k_final<<<1, 256, 0, stream>>>(blockpart, 12500, (float*)d_out);
}

// Round 4
// 1098.363 us; speedup vs baseline: 1.4836x; 1.0335x over previous
//
#include <hip/hip_runtime.h>
#include <math.h>

// Problem constants (from reference)
constexpr int N_NODES = 50000;
constexpr int N_EDGES = 1600000;
constexpr int HDIM    = 64;
constexpr int NLAYER  = 5;
constexpr int NBASIS  = 8;
constexpr int TLUT    = 512;           // radial LUT entries per layer
constexpr float CUT_R = 5.0f;
constexpr float PI_F  = 3.14159265358979f;

__device__ __forceinline__ float bcastf(float v, int l) {
    return __uint_as_float(__builtin_amdgcn_readlane(__float_as_uint(v), l));
}
__device__ __forceinline__ float waveRedSum(float v) {
    for (int off = 32; off > 0; off >>= 1) v += __shfl_xor(v, off, 64);
    return v;
}
__device__ __forceinline__ float siluf(float x) { return x / (1.0f + __expf(-x)); }

// ---------------- setup kernels ----------------

__global__ void k_embed(const int* __restrict__ an, const float* __restrict__ embed,
                        float* __restrict__ feats) {
    int i = blockIdx.x * blockDim.x + threadIdx.x;           // N*H threads
    if (i >= N_NODES * HDIM) return;
    int node = i >> 6, h = i & 63;
    feats[i] = embed[an[node] * HDIM + h];
}

__global__ void k_hist(const int* __restrict__ row, int* __restrict__ counts) {
    int e = blockIdx.x * blockDim.x + threadIdx.x;
    if (e < N_EDGES) atomicAdd(&counts[row[e]], 1);
}

__global__ void k_scan1(const int* __restrict__ counts, int* __restrict__ partial) {
    __shared__ int s[256];
    int i = blockIdx.x * 256 + threadIdx.x;
    int v = (i < N_NODES) ? counts[i] : 0;
    s[threadIdx.x] = v; __syncthreads();
    for (int off = 128; off > 0; off >>= 1) {
        if (threadIdx.x < off) s[threadIdx.x] += s[threadIdx.x + off];
        __syncthreads();
    }
    if (threadIdx.x == 0) partial[blockIdx.x] = s[0];
}

// single-block exclusive scan of block partials (nb <= 256)
__global__ void k_scan2(int* __restrict__ partial, int nb) {
    __shared__ int s[256];
    int v = (threadIdx.x < nb) ? partial[threadIdx.x] : 0;
    s[threadIdx.x] = v; __syncthreads();
    for (int off = 1; off < 256; off <<= 1) {
        int add = (threadIdx.x >= off) ? s[threadIdx.x - off] : 0;
        __syncthreads();
        s[threadIdx.x] += add;
        __syncthreads();
    }
    if (threadIdx.x < nb) partial[threadIdx.x] = s[threadIdx.x] - v;  // exclusive
}

__global__ void k_scan3(const int* __restrict__ counts, const int* __restrict__ partial,
                        int* __restrict__ starts, int* __restrict__ cursor) {
    __shared__ int s[256];
    int i = blockIdx.x * 256 + threadIdx.x;
    int v = (i < N_NODES) ? counts[i] : 0;
    s[threadIdx.x] = v; __syncthreads();
    for (int off = 1; off < 256; off <<= 1) {               // inclusive Hillis-Steele
        int add = (threadIdx.x >= off) ? s[threadIdx.x - off] : 0;
        __syncthreads();
        s[threadIdx.x] += add;
        __syncthreads();
    }
    if (i < N_NODES) {
        int st = partial[blockIdx.x] + s[threadIdx.x] - v;  // exclusive
        starts[i] = st; cursor[i] = st;
    }
    if (i == 0) starts[N_NODES] = N_EDGES;
}

// scatter edges into CSR order, packing (col, t) into 8B records
__global__ void k_scatter(const int* __restrict__ row, const int* __restrict__ col,
                          const float* __restrict__ pos, int* __restrict__ cursor,
                          int2* __restrict__ erec) {
    int e = blockIdx.x * blockDim.x + threadIdx.x;
    if (e >= N_EDGES) return;
    int r = row[e], c = col[e];
    int p = atomicAdd(&cursor[r], 1);
    float dx = pos[c * 3 + 0] - pos[r * 3 + 0];
    float dy = pos[c * 3 + 1] - pos[r * 3 + 1];
    float dz = pos[c * 3 + 2] - pos[r * 3 + 2];
    float len = sqrtf(dx * dx + dy * dy + dz * dz);
    float t = len * ((float)(TLUT - 1) / CUT_R);
    t = fminf(t, (float)(TLUT - 1));        // exact for len>=cutoff (rbf==0 there)
    erec[p] = make_int2(c, __float_as_int(t));
}

// W2s[l][k][h] = sum_{m<3} rad_w2[l][k][h*3+m]; Wsp[l][k][h] = (self_w @ proj_top)[k][h]
__global__ void k_prep(const float* __restrict__ rad_w2, const float* __restrict__ self_w,
                       const float* __restrict__ proj_w,
                       float* __restrict__ W2s, float* __restrict__ Wsp) {
    int i = blockIdx.x * blockDim.x + threadIdx.x;          // L*H*H
    if (i >= NLAYER * HDIM * HDIM) return;
    int l = i / (HDIM * HDIM); int rem = i % (HDIM * HDIM);
    int k = rem / HDIM; int h = rem % HDIM;
    const float* w = rad_w2 + ((size_t)l * HDIM + k) * (HDIM * 3) + h * 3;
    W2s[i] = w[0] + w[1] + w[2];
    const float* sw = self_w + ((size_t)l * HDIM + k) * HDIM;
    const float* pw = proj_w + (size_t)l * 2 * HDIM * HDIM;
    float acc = 0.f;
    for (int m = 0; m < HDIM; ++m) acc += sw[m] * pw[m * HDIM + h];
    Wsp[i] = acc;
}

// b2s[l][h] = sum_m rad_b2[l][h*3+m];  bsp[l][h] = self_b@proj_top + proj_b
__global__ void k_bias(const float* __restrict__ rad_b2, const float* __restrict__ self_b,
                       const float* __restrict__ proj_w, const float* __restrict__ proj_b,
                       float* __restrict__ b2s, float* __restrict__ bsp) {
    int i = blockIdx.x * blockDim.x + threadIdx.x;          // L*H
    if (i >= NLAYER * HDIM) return;
    int l = i / HDIM, h = i % HDIM;
    const float* rb2 = rad_b2 + l * HDIM * 3 + h * 3;
    b2s[i] = rb2[0] + rb2[1] + rb2[2];
    float acc = proj_b[l * HDIM + h];
    const float* pw = proj_w + (size_t)l * 2 * HDIM * HDIM;
    const float* sb = self_b + l * HDIM;
    for (int m = 0; m < HDIM; ++m) acc += sb[m] * pw[m * HDIM + h];
    bsp[i] = acc;
}

// radial LUT: lut[l][t][h] = (silu(rbf(len_t)@W1 + b1) @ W2s + b2s)[h]
__global__ void k_lut(const float* __restrict__ widths, const float* __restrict__ rad_w1,
                      const float* __restrict__ rad_b1, const float* __restrict__ W2s,
                      const float* __restrict__ b2s, float* __restrict__ lut) {
    int bid = blockIdx.x;                 // l*TLUT + t
    int l = bid / TLUT, t = bid % TLUT;
    int h = threadIdx.x;                  // 64 threads
    __shared__ float h1s[HDIM];
    float len = (float)t * (CUT_R / (float)(TLUT - 1));
    float cut = 0.0f;
    if (len < CUT_R) cut = 0.5f * (cosf(len * (PI_F / CUT_R)) + 1.0f);
    float acc = rad_b1[l * HDIM + h];
    for (int b = 0; b < NBASIS; ++b) {
        float wb = fmaxf(widths[b], 0.1f);
        float center = (float)b * (CUT_R / (float)(NBASIS - 1));
        float d = (len - center) / wb;
        float rbf = __expf(-0.5f * d * d) * cut;
        acc += rbf * rad_w1[(l * NBASIS + b) * HDIM + h];
    }
    h1s[h] = siluf(acc);
    __syncthreads();
    float o = b2s[l * HDIM + h];
    const float* w2 = W2s + (size_t)l * HDIM * HDIM;
    for (int k = 0; k < HDIM; ++k) o += h1s[k] * w2[k * HDIM + h];
    lut[(size_t)bid * HDIM + h] = o;
}

// lutQ[(l*TLUT+t)*16+j] = pair {row t ch 4j..4j+3, row t+1 ch 4j..4j+3}
__global__ void k_lutq(const float* __restrict__ lut, float4* __restrict__ lutQ) {
    int i = blockIdx.x * blockDim.x + threadIdx.x;          // L*TLUT*16
    if (i >= NLAYER * TLUT * 16) return;
    int j = i & 15;
    int lt = i >> 4;                       // l*TLUT + t
    int l = lt / TLUT, t = lt % TLUT;
    int t1 = (t < TLUT - 1) ? t + 1 : t;
    const float* r0 = lut + (size_t)(l * TLUT + t)  * HDIM + 4 * j;
    const float* r1 = lut + (size_t)(l * TLUT + t1) * HDIM + 4 * j;
    lutQ[(size_t)i * 2 + 0] = make_float4(r0[0], r0[1], r0[2], r0[3]);
    lutQ[(size_t)i * 2 + 1] = make_float4(r1[0], r1[1], r1[2], r1[3]);
}

// ---------------- per-layer kernels ----------------

// one wave per node, 4 edge slots x 16 lanes (4 channels each via float4)
__global__ __launch_bounds__(256) void k_agg(const float4* __restrict__ feats4,
                                             const float4* __restrict__ lutQ_l,
                                             const int* __restrict__ starts,
                                             const int2* __restrict__ erec,
                                             float4* __restrict__ agg4) {
    int wid  = (blockIdx.x * blockDim.x + threadIdx.x) >> 6;
    int lane = threadIdx.x & 63;
    int slot = lane >> 4;
    int j    = lane & 15;
    if (wid >= N_NODES) return;
    int e0 = starts[wid], e1 = starts[wid + 1];
    float ax = 0.f, ay = 0.f, az = 0.f, aw = 0.f;
    #pragma unroll 2
    for (int e = e0 + slot; e < e1; e += 4) {
        int2  r = erec[e];
        int   c = r.x;
        float t = __int_as_float(r.y);
        int   i0 = (int)t;
        float f  = t - (float)i0;
        const float4* q = lutQ_l + ((size_t)(i0 * 16 + j) * 2);
        float4 w0 = q[0];
        float4 w1 = q[1];
        float4 fv = feats4[(size_t)c * 16 + j];
        ax += fv.x * (w0.x + f * (w1.x - w0.x));
        ay += fv.y * (w0.y + f * (w1.y - w0.y));
        az += fv.z * (w0.z + f * (w1.z - w0.z));
        aw += fv.w * (w0.w + f * (w1.w - w0.w));
    }
    // reduce across the 4 slots (lanes j, j+16, j+32, j+48)
    ax += __shfl_xor(ax, 16, 64);  ay += __shfl_xor(ay, 16, 64);
    az += __shfl_xor(az, 16, 64);  aw += __shfl_xor(aw, 16, 64);
    ax += __shfl_xor(ax, 32, 64);  ay += __shfl_xor(ay, 32, 64);
    az += __shfl_xor(az, 32, 64);  aw += __shfl_xor(aw, 32, 64);
    if (slot == 0) agg4[(size_t)wid * 16 + j] = make_float4(ax, ay, az, aw);
}

// One wave per 64-node tile; lane = output channel. Weights live in per-lane
// VGPR arrays (static index, coalesced loads); matmul k-operands come from
// wave-uniform ds_read_b128 broadcasts. No __syncthreads (intra-wave only).
// LDS tile T[128][64]: rows 0..63 = x (later m1-lo), rows 64..127 = a
// (later conv, later m1-hi).
__global__ __launch_bounds__(64) void k_node(float* __restrict__ feats,
        const float* __restrict__ agg,
        const float* __restrict__ Wsp_l, const float* __restrict__ bsp_l,
        const float* __restrict__ projw_l,
        const float* __restrict__ mlp_w1_l, const float* __restrict__ mlp_b1_l,
        const float* __restrict__ mlp_w2_l, const float* __restrict__ mlp_b2_l,
        const float* __restrict__ ln_g_l, const float* __restrict__ ln_b_l) {
    __shared__ float T[128 * 64];          // 32 KB
    const int lane = threadIdx.x;
    const int nb0  = blockIdx.x * 64;
    const float* pb = projw_l + HDIM * HDIM;   // bottom half of proj_w

    // stage x (rows 0..63) and a (rows 64..127); coalesced, 2-way bank (free)
    #pragma unroll 4
    for (int r = 0; r < 64; ++r) {
        int nd = nb0 + r; nd = (nd < N_NODES) ? nd : (N_NODES - 1);
        T[r * 64 + lane]        = feats[(size_t)nd * 64 + lane];
        T[(64 + r) * 64 + lane] = agg[(size_t)nd * 64 + lane];
    }

    // conv weights: per-lane columns, static-index register arrays
    float Wa[64], Wb[64];
    #pragma unroll
    for (int k = 0; k < 64; ++k) Wa[k] = Wsp_l[k * 64 + lane];
    #pragma unroll
    for (int k = 0; k < 64; ++k) Wb[k] = pb[k * 64 + lane];
    float bspv = bsp_l[lane];

    asm volatile("s_waitcnt lgkmcnt(0)" ::: "memory");

    // conv = bsp + x@Wsp + a@Pb -> store over a-rows (64..127)
    #pragma unroll 1
    for (int r0 = 0; r0 < 64; r0 += 4) {
        float c0 = bspv, c1 = bspv, c2 = bspv, c3 = bspv;
        #pragma unroll
        for (int k = 0; k < 64; k += 4) {
            float4 x0 = *(const float4*)&T[(r0 + 0) * 64 + k];
            float4 x1 = *(const float4*)&T[(r0 + 1) * 64 + k];
            float4 x2 = *(const float4*)&T[(r0 + 2) * 64 + k];
            float4 x3 = *(const float4*)&T[(r0 + 3) * 64 + k];
            c0 = fmaf(x0.x, Wa[k], c0); c0 = fmaf(x0.y, Wa[k+1], c0); c0 = fmaf(x0.z, Wa[k+2], c0); c0 = fmaf(x0.w, Wa[k+3], c0);
            c1 = fmaf(x1.x, Wa[k], c1); c1 = fmaf(x1.y, Wa[k+1], c1); c1 = fmaf(x1.z, Wa[k+2], c1); c1 = fmaf(x1.w, Wa[k+3], c1);
            c2 = fmaf(x2.x, Wa[k], c2); c2 = fmaf(x2.y, Wa[k+1], c2); c2 = fmaf(x2.z, Wa[k+2], c2); c2 = fmaf(x2.w, Wa[k+3], c2);
            c3 = fmaf(x3.x, Wa[k], c3); c3 = fmaf(x3.y, Wa[k+1], c3); c3 = fmaf(x3.z, Wa[k+2], c3); c3 = fmaf(x3.w, Wa[k+3], c3);
        }
        #pragma unroll
        for (int k = 0; k < 64; k += 4) {
            float4 a0 = *(const float4*)&T[(64 + r0 + 0) * 64 + k];
            float4 a1 = *(const float4*)&T[(64 + r0 + 1) * 64 + k];
            float4 a2 = *(const float4*)&T[(64 + r0 + 2) * 64 + k];
            float4 a3 = *(const float4*)&T[(64 + r0 + 3) * 64 + k];
            c0 = fmaf(a0.x, Wb[k], c0); c0 = fmaf(a0.y, Wb[k+1], c0); c0 = fmaf(a0.z, Wb[k+2], c0); c0 = fmaf(a0.w, Wb[k+3], c0);
            c1 = fmaf(a1.x, Wb[k], c1); c1 = fmaf(a1.y, Wb[k+1], c1); c1 = fmaf(a1.z, Wb[k+2], c1); c1 = fmaf(a1.w, Wb[k+3], c1);
            c2 = fmaf(a2.x, Wb[k], c2); c2 = fmaf(a2.y, Wb[k+1], c2); c2 = fmaf(a2.z, Wb[k+2], c2); c2 = fmaf(a2.w, Wb[k+3], c2);
            c3 = fmaf(a3.x, Wb[k], c3); c3 = fmaf(a3.y, Wb[k+1], c3); c3 = fmaf(a3.z, Wb[k+2], c3); c3 = fmaf(a3.w, Wb[k+3], c3);
        }
        T[(64 + r0 + 0) * 64 + lane] = c0;
        T[(64 + r0 + 1) * 64 + lane] = c1;
        T[(64 + r0 + 2) * 64 + lane] = c2;
        T[(64 + r0 + 3) * 64 + lane] = c3;
    }

    // mlp1 weights (reuse Wa/Wb register budget)
    float W1a[64], W1b[64];
    #pragma unroll
    for (int k = 0; k < 64; ++k) W1a[k] = mlp_w1_l[k * 128 + lane];
    #pragma unroll
    for (int k = 0; k < 64; ++k) W1b[k] = mlp_w1_l[k * 128 + 64 + lane];
    float b1a = mlp_b1_l[lane], b1b = mlp_b1_l[64 + lane];

    asm volatile("s_waitcnt lgkmcnt(0)" ::: "memory");

    // m1 = silu(conv@W1 + b1): node r -> row r (ch 0..63) and row 64+r (ch 64..127)
    #pragma unroll 1
    for (int r0 = 0; r0 < 64; r0 += 2) {
        float m00 = b1a, m01 = b1b, m10 = b1a, m11 = b1b;
        #pragma unroll
        for (int k = 0; k < 64; k += 4) {
            float4 x0 = *(const float4*)&T[(64 + r0 + 0) * 64 + k];
            float4 x1 = *(const float4*)&T[(64 + r0 + 1) * 64 + k];
            m00 = fmaf(x0.x, W1a[k], m00); m00 = fmaf(x0.y, W1a[k+1], m00); m00 = fmaf(x0.z, W1a[k+2], m00); m00 = fmaf(x0.w, W1a[k+3], m00);
            m01 = fmaf(x0.x, W1b[k], m01); m01 = fmaf(x0.y, W1b[k+1], m01); m01 = fmaf(x0.z, W1b[k+2], m01); m01 = fmaf(x0.w, W1b[k+3], m01);
            m10 = fmaf(x1.x, W1a[k], m10); m10 = fmaf(x1.y, W1a[k+1], m10); m10 = fmaf(x1.z, W1a[k+2], m10); m10 = fmaf(x1.w, W1a[k+3], m10);
            m11 = fmaf(x1.x, W1b[k], m11); m11 = fmaf(x1.y, W1b[k+1], m11); m11 = fmaf(x1.z, W1b[k+2], m11); m11 = fmaf(x1.w, W1b[k+3], m11);
        }
        T[(r0 + 0) * 64 + lane]      = siluf(m00);
        T[(64 + r0 + 0) * 64 + lane] = siluf(m01);
        T[(r0 + 1) * 64 + lane]      = siluf(m10);
        T[(64 + r0 + 1) * 64 + lane] = siluf(m11);
    }

    // mlp2 weights
    float W2c[128];
    #pragma unroll
    for (int k = 0; k < 128; ++k) W2c[k] = mlp_w2_l[k * 64 + lane];
    float b2v = mlp_b2_l[lane];
    float gv  = ln_g_l[lane], bv = ln_b_l[lane];

    asm volatile("s_waitcnt lgkmcnt(0)" ::: "memory");

    // upd = m1@W2 + b2; then residual + LayerNorm, write feats
    #pragma unroll 1
    for (int r0 = 0; r0 < 64; r0 += 2) {
        float u0 = b2v, u1 = b2v;
        #pragma unroll
        for (int k = 0; k < 64; k += 4) {
            float4 x0 = *(const float4*)&T[(r0 + 0) * 64 + k];
            float4 x1 = *(const float4*)&T[(r0 + 1) * 64 + k];
            u0 = fmaf(x0.x, W2c[k], u0); u0 = fmaf(x0.y, W2c[k+1], u0); u0 = fmaf(x0.z, W2c[k+2], u0); u0 = fmaf(x0.w, W2c[k+3], u0);
            u1 = fmaf(x1.x, W2c[k], u1); u1 = fmaf(x1.y, W2c[k+1], u1); u1 = fmaf(x1.z, W2c[k+2], u1); u1 = fmaf(x1.w, W2c[k+3], u1);
        }
        #pragma unroll
        for (int k = 0; k < 64; k += 4) {
            float4 x0 = *(const float4*)&T[(64 + r0 + 0) * 64 + k];
            float4 x1 = *(const float4*)&T[(64 + r0 + 1) * 64 + k];
            u0 = fmaf(x0.x, W2c[64+k], u0); u0 = fmaf(x0.y, W2c[64+k+1], u0); u0 = fmaf(x0.z, W2c[64+k+2], u0); u0 = fmaf(x0.w, W2c[64+k+3], u0);
            u1 = fmaf(x1.x, W2c[64+k], u1); u1 = fmaf(x1.y, W2c[64+k+1], u1); u1 = fmaf(x1.z, W2c[64+k+2], u1); u1 = fmaf(x1.w, W2c[64+k+3], u1);
        }
        int nd0 = nb0 + r0, nd1 = nb0 + r0 + 1;
        int nd0s = (nd0 < N_NODES) ? nd0 : (N_NODES - 1);
        int nd1s = (nd1 < N_NODES) ? nd1 : (N_NODES - 1);
        float y0 = feats[(size_t)nd0s * 64 + lane] + u0;
        float y1 = feats[(size_t)nd1s * 64 + lane] + u1;
        float p0 = y0, q0 = y0 * y0, p1 = y1, q1 = y1 * y1;
        #pragma unroll
        for (int off = 32; off > 0; off >>= 1) {
            p0 += __shfl_xor(p0, off, 64);  q0 += __shfl_xor(q0, off, 64);
            p1 += __shfl_xor(p1, off, 64);  q1 += __shfl_xor(q1, off, 64);
        }
        float mu0 = p0 * (1.0f / 64.0f), var0 = q0 * (1.0f / 64.0f) - mu0 * mu0;
        float mu1 = p1 * (1.0f / 64.0f), var1 = q1 * (1.0f / 64.0f) - mu1 * mu1;
        float rr0 = rsqrtf(var0 + 1e-5f), rr1 = rsqrtf(var1 + 1e-5f);
        if (nd0 < N_NODES) feats[(size_t)nd0 * 64 + lane] = (y0 - mu0) * rr0 * gv + bv;
        if (nd1 < N_NODES) feats[(size_t)nd1 * 64 + lane] = (y1 - mu1) * rr1 * gv + bv;
    }
}

// ---------------- readout ----------------

__global__ __launch_bounds__(256) void k_readout(const float* __restrict__ feats,
        const int* __restrict__ an,
        const float* __restrict__ ro_w1, const float* __restrict__ ro_b1,
        const float* __restrict__ ro_w2, const float* __restrict__ ro_b2,
        const float* __restrict__ ro_w3, const float* __restrict__ ro_b3,
        const float* __restrict__ atomic_e, float* __restrict__ blockpart) {
    __shared__ float sacc[4];
    int wib  = threadIdx.x >> 6;
    int lane = threadIdx.x & 63;
    int node = blockIdx.x * 4 + wib;
    float e = 0.0f;
    if (node < N_NODES) {
        float x = feats[(size_t)node * HDIM + lane];
        float h1 = ro_b1[lane];
        #pragma unroll 8
        for (int k = 0; k < HDIM; ++k) h1 += bcastf(x, k) * ro_w1[k * HDIM + lane];
        h1 = siluf(h1);
        int j = lane & 31;
        float h2 = ro_b2[j];
        #pragma unroll 8
        for (int k = 0; k < HDIM; ++k) h2 += bcastf(h1, k) * ro_w2[k * 32 + j];
        h2 = siluf(h2);
        float contrib = (lane < 32) ? h2 * ro_w3[j] : 0.0f;
        contrib = waveRedSum(contrib);
        e = contrib + ro_b3[0] + atomic_e[an[node]];
    }
    if (lane == 0) sacc[wib] = e;
    __syncthreads();
    if (threadIdx.x == 0)
        blockpart[blockIdx.x] = sacc[0] + sacc[1] + sacc[2] + sacc[3];
}

__global__ void k_final(const float* __restrict__ blockpart, int nb, float* __restrict__ out) {
    __shared__ float s[256];
    float acc = 0.f;
    for (int i = threadIdx.x; i < nb; i += 256) acc += blockpart[i];
    s[threadIdx.x] = acc; __syncthreads();
    for (int off = 128; off > 0; off >>= 1) {
        if (threadIdx.x < off) s[threadIdx.x] += s[threadIdx.x + off];
        __syncthreads();
    }
    if (threadIdx.x == 0) out[0] = s[0];
}

// ---------------- launch ----------------

extern "C" void kernel_launch(void* const* d_in, const int* in_sizes, int n_in,
                              void* d_out, int out_size, void* d_ws, size_t ws_size,
                              hipStream_t stream) {
    const int*   an       = (const int*)  d_in[0];
    const float* pos      = (const float*)d_in[1];
    const int*   edge     = (const int*)  d_in[2];
    const float* widths   = (const float*)d_in[3];
    const float* embed    = (const float*)d_in[4];
    const float* rad_w1   = (const float*)d_in[5];
    const float* rad_b1   = (const float*)d_in[6];
    const float* rad_w2   = (const float*)d_in[7];
    const float* rad_b2   = (const float*)d_in[8];
    const float* self_w   = (const float*)d_in[9];
    const float* self_b   = (const float*)d_in[10];
    const float* proj_w   = (const float*)d_in[11];
    const float* proj_b   = (const float*)d_in[12];
    const float* mlp_w1   = (const float*)d_in[13];
    const float* mlp_b1   = (const float*)d_in[14];
    const float* mlp_w2   = (const float*)d_in[15];
    const float* mlp_b2   = (const float*)d_in[16];
    const float* ln_g     = (const float*)d_in[17];
    const float* ln_b     = (const float*)d_in[18];
    const float* ro_w1    = (const float*)d_in[19];
    const float* ro_b1    = (const float*)d_in[20];
    const float* ro_w2    = (const float*)d_in[21];
    const float* ro_b2    = (const float*)d_in[22];
    const float* ro_w3    = (const float*)d_in[23];
    const float* ro_b3    = (const float*)d_in[24];
    const float* atomic_e = (const float*)d_in[25];

    char* w = (char*)d_ws;
    auto alloc = [&](size_t bytes) { char* p = w; w += (bytes + 255) & ~(size_t)255; return p; };
    float* feats     = (float*)alloc(sizeof(float) * N_NODES * HDIM);
    float* aggb      = (float*)alloc(sizeof(float) * N_NODES * HDIM);
    float* lut       = (float*)alloc(sizeof(float) * NLAYER * TLUT * HDIM);
    float4* lutQ     = (float4*)alloc(sizeof(float4) * NLAYER * TLUT * 32);
    float* W2s       = (float*)alloc(sizeof(float) * NLAYER * HDIM * HDIM);
    float* b2s       = (float*)alloc(sizeof(float) * NLAYER * HDIM);
    float* Wsp       = (float*)alloc(sizeof(float) * NLAYER * HDIM * HDIM);
    float* bsp       = (float*)alloc(sizeof(float) * NLAYER * HDIM);
    int2*  erec      = (int2*) alloc(sizeof(int2) * N_EDGES);
    int*   starts    = (int*)  alloc(sizeof(int) * (N_NODES + 1));
    int*   cursor    = (int*)  alloc(sizeof(int) * N_NODES);
    int*   counts    = (int*)  alloc(sizeof(int) * N_NODES);
    int*   partial   = (int*)  alloc(sizeof(int) * 256);
    float* blockpart = (float*)alloc(sizeof(float) * 12500);
    (void)ws_size; (void)in_sizes; (void)n_in; (void)out_size;

    const int* erow = edge;
    const int* ecol = edge + N_EDGES;

    hipMemsetAsync(counts, 0, sizeof(int) * N_NODES, stream);
    k_embed<<<12500, 256, 0, stream>>>(an, embed, feats);
    k_hist<<<6250, 256, 0, stream>>>(erow, counts);
    k_scan1<<<196, 256, 0, stream>>>(counts, partial);
    k_scan2<<<1, 256, 0, stream>>>(partial, 196);
    k_scan3<<<196, 256, 0, stream>>>(counts, partial, starts, cursor);
    k_scatter<<<6250, 256, 0, stream>>>(erow, ecol, pos, cursor, erec);
    k_prep<<<80, 256, 0, stream>>>(rad_w2, self_w, proj_w, W2s, Wsp);
    k_bias<<<5, 64, 0, stream>>>(rad_b2, self_b, proj_w, proj_b, b2s, bsp);
    k_lut<<<NLAYER * TLUT, 64, 0, stream>>>(widths, rad_w1, rad_b1, W2s, b2s, lut);
    k_lutq<<<(NLAYER * TLUT * 16 + 255) / 256, 256, 0, stream>>>(lut, lutQ);

    for (int l = 0; l < NLAYER; ++l) {
        k_agg<<<12500, 256, 0, stream>>>((const float4*)feats,
                                         lutQ + (size_t)l * TLUT * 32,
                                         starts, erec, (float4*)aggb);
        k_node<<<782, 64, 0, stream>>>(feats, aggb,
            Wsp + (size_t)l * HDIM * HDIM, bsp + l * HDIM,
            proj_w + (size_t)l * 2 * HDIM * HDIM,
            mlp_w1 + (size_t)l * HDIM * 2 * HDIM, mlp_b1 + l * 2 * HDIM,
            mlp_w2 + (size_t)l * 2 * HDIM * HDIM, mlp_b2 + l * HDIM,
            ln_g + l * HDIM, ln_b + l * HDIM);
    }

    k_readout<<<12500, 256, 0, stream>>>(feats, an, ro_w1, ro_b1, ro_w2, ro_b2,
                                         ro_w3, ro_b3, atomic_e, blockpart);
    k_final<<<1, 256, 0, stream>>>(blockpart, 12500, (float*)d_out);
}

// Round 5
// 902.516 us; speedup vs baseline: 1.8056x; 1.2170x over previous
//
#include <hip/hip_runtime.h>
#include <math.h>

// Problem constants (from reference)
constexpr int N_NODES = 50000;
constexpr int N_EDGES = 1600000;
constexpr int HDIM    = 64;
constexpr int NLAYER  = 5;
constexpr int NBASIS  = 8;
constexpr int TLUT    = 512;           // radial LUT entries per layer
constexpr float CUT_R = 5.0f;
constexpr float PI_F  = 3.14159265358979f;

__device__ __forceinline__ float bcastf(float v, int l) {
    return __uint_as_float(__builtin_amdgcn_readlane(__float_as_uint(v), l));
}
__device__ __forceinline__ float waveRedSum(float v) {
    for (int off = 32; off > 0; off >>= 1) v += __shfl_xor(v, off, 64);
    return v;
}
__device__ __forceinline__ float siluf(float x) { return x / (1.0f + __expf(-x)); }

// ---------------- setup kernels ----------------

__global__ void k_embed(const int* __restrict__ an, const float* __restrict__ embed,
                        float* __restrict__ feats) {
    int i = blockIdx.x * blockDim.x + threadIdx.x;           // N*H threads
    if (i >= N_NODES * HDIM) return;
    int node = i >> 6, h = i & 63;
    feats[i] = embed[an[node] * HDIM + h];
}

__global__ void k_hist(const int* __restrict__ row, int* __restrict__ counts) {
    int e = blockIdx.x * blockDim.x + threadIdx.x;
    if (e < N_EDGES) atomicAdd(&counts[row[e]], 1);
}

__global__ void k_scan1(const int* __restrict__ counts, int* __restrict__ partial) {
    __shared__ int s[256];
    int i = blockIdx.x * 256 + threadIdx.x;
    int v = (i < N_NODES) ? counts[i] : 0;
    s[threadIdx.x] = v; __syncthreads();
    for (int off = 128; off > 0; off >>= 1) {
        if (threadIdx.x < off) s[threadIdx.x] += s[threadIdx.x + off];
        __syncthreads();
    }
    if (threadIdx.x == 0) partial[blockIdx.x] = s[0];
}

// single-block exclusive scan of block partials (nb <= 256)
__global__ void k_scan2(int* __restrict__ partial, int nb) {
    __shared__ int s[256];
    int v = (threadIdx.x < nb) ? partial[threadIdx.x] : 0;
    s[threadIdx.x] = v; __syncthreads();
    for (int off = 1; off < 256; off <<= 1) {
        int add = (threadIdx.x >= off) ? s[threadIdx.x - off] : 0;
        __syncthreads();
        s[threadIdx.x] += add;
        __syncthreads();
    }
    if (threadIdx.x < nb) partial[threadIdx.x] = s[threadIdx.x] - v;  // exclusive
}

__global__ void k_scan3(const int* __restrict__ counts, const int* __restrict__ partial,
                        int* __restrict__ starts, int* __restrict__ cursor) {
    __shared__ int s[256];
    int i = blockIdx.x * 256 + threadIdx.x;
    int v = (i < N_NODES) ? counts[i] : 0;
    s[threadIdx.x] = v; __syncthreads();
    for (int off = 1; off < 256; off <<= 1) {               // inclusive Hillis-Steele
        int add = (threadIdx.x >= off) ? s[threadIdx.x - off] : 0;
        __syncthreads();
        s[threadIdx.x] += add;
        __syncthreads();
    }
    if (i < N_NODES) {
        int st = partial[blockIdx.x] + s[threadIdx.x] - v;  // exclusive
        starts[i] = st; cursor[i] = st;
    }
    if (i == 0) starts[N_NODES] = N_EDGES;
}

// scatter edges into CSR order, packing (col, t) into 8B records
__global__ void k_scatter(const int* __restrict__ row, const int* __restrict__ col,
                          const float* __restrict__ pos, int* __restrict__ cursor,
                          int2* __restrict__ erec) {
    int e = blockIdx.x * blockDim.x + threadIdx.x;
    if (e >= N_EDGES) return;
    int r = row[e], c = col[e];
    int p = atomicAdd(&cursor[r], 1);
    float dx = pos[c * 3 + 0] - pos[r * 3 + 0];
    float dy = pos[c * 3 + 1] - pos[r * 3 + 1];
    float dz = pos[c * 3 + 2] - pos[r * 3 + 2];
    float len = sqrtf(dx * dx + dy * dy + dz * dz);
    float t = len * ((float)(TLUT - 1) / CUT_R);
    t = fminf(t, (float)(TLUT - 1));        // exact for len>=cutoff (rbf==0 there)
    erec[p] = make_int2(c, __float_as_int(t));
}

// W2s[l][k][h] = sum_{m<3} rad_w2[l][k][h*3+m]; Wsp[l][k][h] = (self_w @ proj_top)[k][h]
__global__ void k_prep(const float* __restrict__ rad_w2, const float* __restrict__ self_w,
                       const float* __restrict__ proj_w,
                       float* __restrict__ W2s, float* __restrict__ Wsp) {
    int i = blockIdx.x * blockDim.x + threadIdx.x;          // L*H*H
    if (i >= NLAYER * HDIM * HDIM) return;
    int l = i / (HDIM * HDIM); int rem = i % (HDIM * HDIM);
    int k = rem / HDIM; int h = rem % HDIM;
    const float* w = rad_w2 + ((size_t)l * HDIM + k) * (HDIM * 3) + h * 3;
    W2s[i] = w[0] + w[1] + w[2];
    const float* sw = self_w + ((size_t)l * HDIM + k) * HDIM;
    const float* pw = proj_w + (size_t)l * 2 * HDIM * HDIM;
    float acc = 0.f;
    for (int m = 0; m < HDIM; ++m) acc += sw[m] * pw[m * HDIM + h];
    Wsp[i] = acc;
}

// b2s[l][h] = sum_m rad_b2[l][h*3+m];  bsp[l][h] = self_b@proj_top + proj_b
__global__ void k_bias(const float* __restrict__ rad_b2, const float* __restrict__ self_b,
                       const float* __restrict__ proj_w, const float* __restrict__ proj_b,
                       float* __restrict__ b2s, float* __restrict__ bsp) {
    int i = blockIdx.x * blockDim.x + threadIdx.x;          // L*H
    if (i >= NLAYER * HDIM) return;
    int l = i / HDIM, h = i % HDIM;
    const float* rb2 = rad_b2 + l * HDIM * 3 + h * 3;
    b2s[i] = rb2[0] + rb2[1] + rb2[2];
    float acc = proj_b[l * HDIM + h];
    const float* pw = proj_w + (size_t)l * 2 * HDIM * HDIM;
    const float* sb = self_b + l * HDIM;
    for (int m = 0; m < HDIM; ++m) acc += sb[m] * pw[m * HDIM + h];
    bsp[i] = acc;
}

// radial LUT: lut[l][t][h] = (silu(rbf(len_t)@W1 + b1) @ W2s + b2s)[h]
__global__ void k_lut(const float* __restrict__ widths, const float* __restrict__ rad_w1,
                      const float* __restrict__ rad_b1, const float* __restrict__ W2s,
                      const float* __restrict__ b2s, float* __restrict__ lut) {
    int bid = blockIdx.x;                 // l*TLUT + t
    int l = bid / TLUT, t = bid % TLUT;
    int h = threadIdx.x;                  // 64 threads
    __shared__ float h1s[HDIM];
    float len = (float)t * (CUT_R / (float)(TLUT - 1));
    float cut = 0.0f;
    if (len < CUT_R) cut = 0.5f * (cosf(len * (PI_F / CUT_R)) + 1.0f);
    float acc = rad_b1[l * HDIM + h];
    for (int b = 0; b < NBASIS; ++b) {
        float wb = fmaxf(widths[b], 0.1f);
        float center = (float)b * (CUT_R / (float)(NBASIS - 1));
        float d = (len - center) / wb;
        float rbf = __expf(-0.5f * d * d) * cut;
        acc += rbf * rad_w1[(l * NBASIS + b) * HDIM + h];
    }
    h1s[h] = siluf(acc);
    __syncthreads();
    float o = b2s[l * HDIM + h];
    const float* w2 = W2s + (size_t)l * HDIM * HDIM;
    for (int k = 0; k < HDIM; ++k) o += h1s[k] * w2[k * HDIM + h];
    lut[(size_t)bid * HDIM + h] = o;
}

// lutQ[(l*TLUT+t)*16+j] = pair {row t ch 4j..4j+3, row t+1 ch 4j..4j+3}
__global__ void k_lutq(const float* __restrict__ lut, float4* __restrict__ lutQ) {
    int i = blockIdx.x * blockDim.x + threadIdx.x;          // L*TLUT*16
    if (i >= NLAYER * TLUT * 16) return;
    int j = i & 15;
    int lt = i >> 4;                       // l*TLUT + t
    int l = lt / TLUT, t = lt % TLUT;
    int t1 = (t < TLUT - 1) ? t + 1 : t;
    const float* r0 = lut + (size_t)(l * TLUT + t)  * HDIM + 4 * j;
    const float* r1 = lut + (size_t)(l * TLUT + t1) * HDIM + 4 * j;
    lutQ[(size_t)i * 2 + 0] = make_float4(r0[0], r0[1], r0[2], r0[3]);
    lutQ[(size_t)i * 2 + 1] = make_float4(r1[0], r1[1], r1[2], r1[3]);
}

// ---------------- per-layer kernels ----------------

// one wave per node, 4 edge slots x 16 lanes (4 channels each via float4)
__global__ __launch_bounds__(256) void k_agg(const float4* __restrict__ feats4,
                                             const float4* __restrict__ lutQ_l,
                                             const int* __restrict__ starts,
                                             const int2* __restrict__ erec,
                                             float4* __restrict__ agg4) {
    int wid  = (blockIdx.x * blockDim.x + threadIdx.x) >> 6;
    int lane = threadIdx.x & 63;
    int slot = lane >> 4;
    int j    = lane & 15;
    if (wid >= N_NODES) return;
    int e0 = starts[wid], e1 = starts[wid + 1];
    float ax = 0.f, ay = 0.f, az = 0.f, aw = 0.f;
    #pragma unroll 2
    for (int e = e0 + slot; e < e1; e += 4) {
        int2  r = erec[e];
        int   c = r.x;
        float t = __int_as_float(r.y);
        int   i0 = (int)t;
        float f  = t - (float)i0;
        const float4* q = lutQ_l + ((size_t)(i0 * 16 + j) * 2);
        float4 w0 = q[0];
        float4 w1 = q[1];
        float4 fv = feats4[(size_t)c * 16 + j];
        ax += fv.x * (w0.x + f * (w1.x - w0.x));
        ay += fv.y * (w0.y + f * (w1.y - w0.y));
        az += fv.z * (w0.z + f * (w1.z - w0.z));
        aw += fv.w * (w0.w + f * (w1.w - w0.w));
    }
    // reduce across the 4 slots (lanes j, j+16, j+32, j+48)
    ax += __shfl_xor(ax, 16, 64);  ay += __shfl_xor(ay, 16, 64);
    az += __shfl_xor(az, 16, 64);  aw += __shfl_xor(aw, 16, 64);
    ax += __shfl_xor(ax, 32, 64);  ay += __shfl_xor(ay, 32, 64);
    az += __shfl_xor(az, 32, 64);  aw += __shfl_xor(aw, 32, 64);
    if (slot == 0) agg4[(size_t)wid * 16 + j] = make_float4(ax, ay, az, aw);
}

// 4 waves/block, 16 nodes per wave; lane = output channel. Weights in per-lane
// VGPR arrays (static index); matmul k-operands via wave-uniform ds_read_b128
// broadcasts from a private 8KB LDS region per wave. No __syncthreads needed.
// Per-wave tile T[32][64]: rows 0..15 = x (later m1-lo), rows 16..31 = a
// (later conv, later m1-hi).
constexpr int NPW = 16;                    // nodes per wave
__global__ __launch_bounds__(256) void k_node(float* __restrict__ feats,
        const float* __restrict__ agg,
        const float* __restrict__ Wsp_l, const float* __restrict__ bsp_l,
        const float* __restrict__ projw_l,
        const float* __restrict__ mlp_w1_l, const float* __restrict__ mlp_b1_l,
        const float* __restrict__ mlp_w2_l, const float* __restrict__ mlp_b2_l,
        const float* __restrict__ ln_g_l, const float* __restrict__ ln_b_l) {
    __shared__ float Tall[4 * 2 * NPW * 64];   // 32 KB (4 waves x 8 KB)
    const int lane = threadIdx.x & 63;
    const int wib  = threadIdx.x >> 6;
    float* T = Tall + wib * (2 * NPW * 64);
    const int nb0 = blockIdx.x * (4 * NPW) + wib * NPW;
    const float* pb = projw_l + HDIM * HDIM;   // bottom half of proj_w

    // stage x (rows 0..15) and a (rows 16..31); coalesced, 2-way bank (free)
    #pragma unroll 4
    for (int r = 0; r < NPW; ++r) {
        int nd = nb0 + r; nd = (nd < N_NODES) ? nd : (N_NODES - 1);
        T[r * 64 + lane]         = feats[(size_t)nd * 64 + lane];
        T[(NPW + r) * 64 + lane] = agg[(size_t)nd * 64 + lane];
    }

    // conv weights: per-lane columns, static-index register arrays
    float Wa[64], Wb[64];
    #pragma unroll
    for (int k = 0; k < 64; ++k) Wa[k] = Wsp_l[k * 64 + lane];
    #pragma unroll
    for (int k = 0; k < 64; ++k) Wb[k] = pb[k * 64 + lane];
    float bspv = bsp_l[lane];

    asm volatile("s_waitcnt lgkmcnt(0)" ::: "memory");

    // conv = bsp + x@Wsp + a@Pb -> store over a-rows (16..31)
    #pragma unroll 1
    for (int r0 = 0; r0 < NPW; r0 += 4) {
        float c0 = bspv, c1 = bspv, c2 = bspv, c3 = bspv;
        #pragma unroll
        for (int k = 0; k < 64; k += 4) {
            float4 x0 = *(const float4*)&T[(r0 + 0) * 64 + k];
            float4 x1 = *(const float4*)&T[(r0 + 1) * 64 + k];
            float4 x2 = *(const float4*)&T[(r0 + 2) * 64 + k];
            float4 x3 = *(const float4*)&T[(r0 + 3) * 64 + k];
            c0 = fmaf(x0.x, Wa[k], c0); c0 = fmaf(x0.y, Wa[k+1], c0); c0 = fmaf(x0.z, Wa[k+2], c0); c0 = fmaf(x0.w, Wa[k+3], c0);
            c1 = fmaf(x1.x, Wa[k], c1); c1 = fmaf(x1.y, Wa[k+1], c1); c1 = fmaf(x1.z, Wa[k+2], c1); c1 = fmaf(x1.w, Wa[k+3], c1);
            c2 = fmaf(x2.x, Wa[k], c2); c2 = fmaf(x2.y, Wa[k+1], c2); c2 = fmaf(x2.z, Wa[k+2], c2); c2 = fmaf(x2.w, Wa[k+3], c2);
            c3 = fmaf(x3.x, Wa[k], c3); c3 = fmaf(x3.y, Wa[k+1], c3); c3 = fmaf(x3.z, Wa[k+2], c3); c3 = fmaf(x3.w, Wa[k+3], c3);
        }
        #pragma unroll
        for (int k = 0; k < 64; k += 4) {
            float4 a0 = *(const float4*)&T[(NPW + r0 + 0) * 64 + k];
            float4 a1 = *(const float4*)&T[(NPW + r0 + 1) * 64 + k];
            float4 a2 = *(const float4*)&T[(NPW + r0 + 2) * 64 + k];
            float4 a3 = *(const float4*)&T[(NPW + r0 + 3) * 64 + k];
            c0 = fmaf(a0.x, Wb[k], c0); c0 = fmaf(a0.y, Wb[k+1], c0); c0 = fmaf(a0.z, Wb[k+2], c0); c0 = fmaf(a0.w, Wb[k+3], c0);
            c1 = fmaf(a1.x, Wb[k], c1); c1 = fmaf(a1.y, Wb[k+1], c1); c1 = fmaf(a1.z, Wb[k+2], c1); c1 = fmaf(a1.w, Wb[k+3], c1);
            c2 = fmaf(a2.x, Wb[k], c2); c2 = fmaf(a2.y, Wb[k+1], c2); c2 = fmaf(a2.z, Wb[k+2], c2); c2 = fmaf(a2.w, Wb[k+3], c2);
            c3 = fmaf(a3.x, Wb[k], c3); c3 = fmaf(a3.y, Wb[k+1], c3); c3 = fmaf(a3.z, Wb[k+2], c3); c3 = fmaf(a3.w, Wb[k+3], c3);
        }
        T[(NPW + r0 + 0) * 64 + lane] = c0;
        T[(NPW + r0 + 1) * 64 + lane] = c1;
        T[(NPW + r0 + 2) * 64 + lane] = c2;
        T[(NPW + r0 + 3) * 64 + lane] = c3;
    }

    // mlp1 weights (reuse Wa/Wb register budget)
    float W1a[64], W1b[64];
    #pragma unroll
    for (int k = 0; k < 64; ++k) W1a[k] = mlp_w1_l[k * 128 + lane];
    #pragma unroll
    for (int k = 0; k < 64; ++k) W1b[k] = mlp_w1_l[k * 128 + 64 + lane];
    float b1a = mlp_b1_l[lane], b1b = mlp_b1_l[64 + lane];

    asm volatile("s_waitcnt lgkmcnt(0)" ::: "memory");

    // m1 = silu(conv@W1 + b1): node r -> row r (ch 0..63) and row NPW+r (ch 64..127)
    #pragma unroll 1
    for (int r0 = 0; r0 < NPW; r0 += 2) {
        float m00 = b1a, m01 = b1b, m10 = b1a, m11 = b1b;
        #pragma unroll
        for (int k = 0; k < 64; k += 4) {
            float4 x0 = *(const float4*)&T[(NPW + r0 + 0) * 64 + k];
            float4 x1 = *(const float4*)&T[(NPW + r0 + 1) * 64 + k];
            m00 = fmaf(x0.x, W1a[k], m00); m00 = fmaf(x0.y, W1a[k+1], m00); m00 = fmaf(x0.z, W1a[k+2], m00); m00 = fmaf(x0.w, W1a[k+3], m00);
            m01 = fmaf(x0.x, W1b[k], m01); m01 = fmaf(x0.y, W1b[k+1], m01); m01 = fmaf(x0.z, W1b[k+2], m01); m01 = fmaf(x0.w, W1b[k+3], m01);
            m10 = fmaf(x1.x, W1a[k], m10); m10 = fmaf(x1.y, W1a[k+1], m10); m10 = fmaf(x1.z, W1a[k+2], m10); m10 = fmaf(x1.w, W1a[k+3], m10);
            m11 = fmaf(x1.x, W1b[k], m11); m11 = fmaf(x1.y, W1b[k+1], m11); m11 = fmaf(x1.z, W1b[k+2], m11); m11 = fmaf(x1.w, W1b[k+3], m11);
        }
        T[(r0 + 0) * 64 + lane]       = siluf(m00);
        T[(NPW + r0 + 0) * 64 + lane] = siluf(m01);
        T[(r0 + 1) * 64 + lane]       = siluf(m10);
        T[(NPW + r0 + 1) * 64 + lane] = siluf(m11);
    }

    // mlp2 weights
    float W2c[128];
    #pragma unroll
    for (int k = 0; k < 128; ++k) W2c[k] = mlp_w2_l[k * 64 + lane];
    float b2v = mlp_b2_l[lane];
    float gv  = ln_g_l[lane], bv = ln_b_l[lane];

    asm volatile("s_waitcnt lgkmcnt(0)" ::: "memory");

    // upd = m1@W2 + b2; then residual + LayerNorm, write feats
    #pragma unroll 1
    for (int r0 = 0; r0 < NPW; r0 += 2) {
        float u0 = b2v, u1 = b2v;
        #pragma unroll
        for (int k = 0; k < 64; k += 4) {
            float4 x0 = *(const float4*)&T[(r0 + 0) * 64 + k];
            float4 x1 = *(const float4*)&T[(r0 + 1) * 64 + k];
            u0 = fmaf(x0.x, W2c[k], u0); u0 = fmaf(x0.y, W2c[k+1], u0); u0 = fmaf(x0.z, W2c[k+2], u0); u0 = fmaf(x0.w, W2c[k+3], u0);
            u1 = fmaf(x1.x, W2c[k], u1); u1 = fmaf(x1.y, W2c[k+1], u1); u1 = fmaf(x1.z, W2c[k+2], u1); u1 = fmaf(x1.w, W2c[k+3], u1);
        }
        #pragma unroll
        for (int k = 0; k < 64; k += 4) {
            float4 x0 = *(const float4*)&T[(NPW + r0 + 0) * 64 + k];
            float4 x1 = *(const float4*)&T[(NPW + r0 + 1) * 64 + k];
            u0 = fmaf(x0.x, W2c[64+k], u0); u0 = fmaf(x0.y, W2c[64+k+1], u0); u0 = fmaf(x0.z, W2c[64+k+2], u0); u0 = fmaf(x0.w, W2c[64+k+3], u0);
            u1 = fmaf(x1.x, W2c[64+k], u1); u1 = fmaf(x1.y, W2c[64+k+1], u1); u1 = fmaf(x1.z, W2c[64+k+2], u1); u1 = fmaf(x1.w, W2c[64+k+3], u1);
        }
        int nd0 = nb0 + r0, nd1 = nb0 + r0 + 1;
        int nd0s = (nd0 < N_NODES) ? nd0 : (N_NODES - 1);
        int nd1s = (nd1 < N_NODES) ? nd1 : (N_NODES - 1);
        float y0 = feats[(size_t)nd0s * 64 + lane] + u0;
        float y1 = feats[(size_t)nd1s * 64 + lane] + u1;
        float p0 = y0, q0 = y0 * y0, p1 = y1, q1 = y1 * y1;
        #pragma unroll
        for (int off = 32; off > 0; off >>= 1) {
            p0 += __shfl_xor(p0, off, 64);  q0 += __shfl_xor(q0, off, 64);
            p1 += __shfl_xor(p1, off, 64);  q1 += __shfl_xor(q1, off, 64);
        }
        float mu0 = p0 * (1.0f / 64.0f), var0 = q0 * (1.0f / 64.0f) - mu0 * mu0;
        float mu1 = p1 * (1.0f / 64.0f), var1 = q1 * (1.0f / 64.0f) - mu1 * mu1;
        float rr0 = rsqrtf(var0 + 1e-5f), rr1 = rsqrtf(var1 + 1e-5f);
        if (nd0 < N_NODES) feats[(size_t)nd0 * 64 + lane] = (y0 - mu0) * rr0 * gv + bv;
        if (nd1 < N_NODES) feats[(size_t)nd1 * 64 + lane] = (y1 - mu1) * rr1 * gv + bv;
    }
}

// ---------------- readout ----------------

__global__ __launch_bounds__(256) void k_readout(const float* __restrict__ feats,
        const int* __restrict__ an,
        const float* __restrict__ ro_w1, const float* __restrict__ ro_b1,
        const float* __restrict__ ro_w2, const float* __restrict__ ro_b2,
        const float* __restrict__ ro_w3, const float* __restrict__ ro_b3,
        const float* __restrict__ atomic_e, float* __restrict__ blockpart) {
    __shared__ float sacc[4];
    int wib  = threadIdx.x >> 6;
    int lane = threadIdx.x & 63;
    int node = blockIdx.x * 4 + wib;
    float e = 0.0f;
    if (node < N_NODES) {
        float x = feats[(size_t)node * HDIM + lane];
        float h1 = ro_b1[lane];
        #pragma unroll 8
        for (int k = 0; k < HDIM; ++k) h1 += bcastf(x, k) * ro_w1[k * HDIM + lane];
        h1 = siluf(h1);
        int j = lane & 31;
        float h2 = ro_b2[j];
        #pragma unroll 8
        for (int k = 0; k < HDIM; ++k) h2 += bcastf(h1, k) * ro_w2[k * 32 + j];
        h2 = siluf(h2);
        float contrib = (lane < 32) ? h2 * ro_w3[j] : 0.0f;
        contrib = waveRedSum(contrib);
        e = contrib + ro_b3[0] + atomic_e[an[node]];
    }
    if (lane == 0) sacc[wib] = e;
    __syncthreads();
    if (threadIdx.x == 0)
        blockpart[blockIdx.x] = sacc[0] + sacc[1] + sacc[2] + sacc[3];
}

__global__ void k_final(const float* __restrict__ blockpart, int nb, float* __restrict__ out) {
    __shared__ float s[256];
    float acc = 0.f;
    for (int i = threadIdx.x; i < nb; i += 256) acc += blockpart[i];
    s[threadIdx.x] = acc; __syncthreads();
    for (int off = 128; off > 0; off >>= 1) {
        if (threadIdx.x < off) s[threadIdx.x] += s[threadIdx.x + off];
        __syncthreads();
    }
    if (threadIdx.x == 0) out[0] = s[0];
}

// ---------------- launch ----------------

extern "C" void kernel_launch(void* const* d_in, const int* in_sizes, int n_in,
                              void* d_out, int out_size, void* d_ws, size_t ws_size,
                              hipStream_t stream) {
    const int*   an       = (const int*)  d_in[0];
    const float* pos      = (const float*)d_in[1];
    const int*   edge     = (const int*)  d_in[2];
    const float* widths   = (const float*)d_in[3];
    const float* embed    = (const float*)d_in[4];
    const float* rad_w1   = (const float*)d_in[5];
    const float* rad_b1   = (const float*)d_in[6];
    const float* rad_w2   = (const float*)d_in[7];
    const float* rad_b2   = (const float*)d_in[8];
    const float* self_w   = (const float*)d_in[9];
    const float* self_b   = (const float*)d_in[10];
    const float* proj_w   = (const float*)d_in[11];
    const float* proj_b   = (const float*)d_in[12];
    const float* mlp_w1   = (const float*)d_in[13];
    const float* mlp_b1   = (const float*)d_in[14];
    const float* mlp_w2   = (const float*)d_in[15];
    const float* mlp_b2   = (const float*)d_in[16];
    const float* ln_g     = (const float*)d_in[17];
    const float* ln_b     = (const float*)d_in[18];
    const float* ro_w1    = (const float*)d_in[19];
    const float* ro_b1    = (const float*)d_in[20];
    const float* ro_w2    = (const float*)d_in[21];
    const float* ro_b2    = (const float*)d_in[22];
    const float* ro_w3    = (const float*)d_in[23];
    const float* ro_b3    = (const float*)d_in[24];
    const float* atomic_e = (const float*)d_in[25];

    char* w = (char*)d_ws;
    auto alloc = [&](size_t bytes) { char* p = w; w += (bytes + 255) & ~(size_t)255; return p; };
    float* feats     = (float*)alloc(sizeof(float) * N_NODES * HDIM);
    float* aggb      = (float*)alloc(sizeof(float) * N_NODES * HDIM);
    float* lut       = (float*)alloc(sizeof(float) * NLAYER * TLUT * HDIM);
    float4* lutQ     = (float4*)alloc(sizeof(float4) * NLAYER * TLUT * 32);
    float* W2s       = (float*)alloc(sizeof(float) * NLAYER * HDIM * HDIM);
    float* b2s       = (float*)alloc(sizeof(float) * NLAYER * HDIM);
    float* Wsp       = (float*)alloc(sizeof(float) * NLAYER * HDIM * HDIM);
    float* bsp       = (float*)alloc(sizeof(float) * NLAYER * HDIM);
    int2*  erec      = (int2*) alloc(sizeof(int2) * N_EDGES);
    int*   starts    = (int*)  alloc(sizeof(int) * (N_NODES + 1));
    int*   cursor    = (int*)  alloc(sizeof(int) * N_NODES);
    int*   counts    = (int*)  alloc(sizeof(int) * N_NODES);
    int*   partial   = (int*)  alloc(sizeof(int) * 256);
    float* blockpart = (float*)alloc(sizeof(float) * 12500);
    (void)ws_size; (void)in_sizes; (void)n_in; (void)out_size;

    const int* erow = edge;
    const int* ecol = edge + N_EDGES;

    hipMemsetAsync(counts, 0, sizeof(int) * N_NODES, stream);
    k_embed<<<12500, 256, 0, stream>>>(an, embed, feats);
    k_hist<<<6250, 256, 0, stream>>>(erow, counts);
    k_scan1<<<196, 256, 0, stream>>>(counts, partial);
    k_scan2<<<1, 256, 0, stream>>>(partial, 196);
    k_scan3<<<196, 256, 0, stream>>>(counts, partial, starts, cursor);
    k_scatter<<<6250, 256, 0, stream>>>(erow, ecol, pos, cursor, erec);
    k_prep<<<80, 256, 0, stream>>>(rad_w2, self_w, proj_w, W2s, Wsp);
    k_bias<<<5, 64, 0, stream>>>(rad_b2, self_b, proj_w, proj_b, b2s, bsp);
    k_lut<<<NLAYER * TLUT, 64, 0, stream>>>(widths, rad_w1, rad_b1, W2s, b2s, lut);
    k_lutq<<<(NLAYER * TLUT * 16 + 255) / 256, 256, 0, stream>>>(lut, lutQ);

    for (int l = 0; l < NLAYER; ++l) {
        k_agg<<<12500, 256, 0, stream>>>((const float4*)feats,
                                         lutQ + (size_t)l * TLUT * 32,
                                         starts, erec, (float4*)aggb);
        k_node<<<782, 256, 0, stream>>>(feats, aggb,
            Wsp + (size_t)l * HDIM * HDIM, bsp + l * HDIM,
            proj_w + (size_t)l * 2 * HDIM * HDIM,
            mlp_w1 + (size_t)l * HDIM * 2 * HDIM, mlp_b1 + l * 2 * HDIM,
            mlp_w2 + (size_t)l * 2 * HDIM * HDIM, mlp_b2 + l * HDIM,
            ln_g + l * HDIM, ln_b + l * HDIM);
    }

    k_readout<<<12500, 256, 0, stream>>>(feats, an, ro_w1, ro_b1, ro_w2, ro_b2,
                                         ro_w3, ro_b3, atomic_e, blockpart);
    k_final<<<1, 256, 0, stream>>>(blockpart, 12500, (float*)d_out);
}

// Round 6
// 874.493 us; speedup vs baseline: 1.8634x; 1.0320x over previous
//
#include <hip/hip_runtime.h>
#include <math.h>

// Problem constants (from reference)
constexpr int N_NODES = 50000;
constexpr int N_EDGES = 1600000;
constexpr int HDIM    = 64;
constexpr int NLAYER  = 5;
constexpr int NBASIS  = 8;
constexpr int TLUT    = 512;           // radial LUT entries per layer
constexpr float CUT_R = 5.0f;
constexpr float PI_F  = 3.14159265358979f;

__device__ __forceinline__ float bcastf(float v, int l) {
    return __uint_as_float(__builtin_amdgcn_readlane(__float_as_uint(v), l));
}
__device__ __forceinline__ float waveRedSum(float v) {
    for (int off = 32; off > 0; off >>= 1) v += __shfl_xor(v, off, 64);
    return v;
}
__device__ __forceinline__ float siluf(float x) { return x / (1.0f + __expf(-x)); }

// ---------------- setup kernels ----------------

__global__ void k_embed(const int* __restrict__ an, const float* __restrict__ embed,
                        float* __restrict__ feats) {
    int i = blockIdx.x * blockDim.x + threadIdx.x;           // N*H threads
    if (i >= N_NODES * HDIM) return;
    int node = i >> 6, h = i & 63;
    feats[i] = embed[an[node] * HDIM + h];
}

__global__ void k_hist(const int* __restrict__ row, int* __restrict__ counts) {
    int e = blockIdx.x * blockDim.x + threadIdx.x;
    if (e < N_EDGES) atomicAdd(&counts[row[e]], 1);
}

__global__ void k_scan1(const int* __restrict__ counts, int* __restrict__ partial) {
    __shared__ int s[256];
    int i = blockIdx.x * 256 + threadIdx.x;
    int v = (i < N_NODES) ? counts[i] : 0;
    s[threadIdx.x] = v; __syncthreads();
    for (int off = 128; off > 0; off >>= 1) {
        if (threadIdx.x < off) s[threadIdx.x] += s[threadIdx.x + off];
        __syncthreads();
    }
    if (threadIdx.x == 0) partial[blockIdx.x] = s[0];
}

// single-block exclusive scan of block partials (nb <= 256)
__global__ void k_scan2(int* __restrict__ partial, int nb) {
    __shared__ int s[256];
    int v = (threadIdx.x < nb) ? partial[threadIdx.x] : 0;
    s[threadIdx.x] = v; __syncthreads();
    for (int off = 1; off < 256; off <<= 1) {
        int add = (threadIdx.x >= off) ? s[threadIdx.x - off] : 0;
        __syncthreads();
        s[threadIdx.x] += add;
        __syncthreads();
    }
    if (threadIdx.x < nb) partial[threadIdx.x] = s[threadIdx.x] - v;  // exclusive
}

__global__ void k_scan3(const int* __restrict__ counts, const int* __restrict__ partial,
                        int* __restrict__ starts, int* __restrict__ cursor) {
    __shared__ int s[256];
    int i = blockIdx.x * 256 + threadIdx.x;
    int v = (i < N_NODES) ? counts[i] : 0;
    s[threadIdx.x] = v; __syncthreads();
    for (int off = 1; off < 256; off <<= 1) {               // inclusive Hillis-Steele
        int add = (threadIdx.x >= off) ? s[threadIdx.x - off] : 0;
        __syncthreads();
        s[threadIdx.x] += add;
        __syncthreads();
    }
    if (i < N_NODES) {
        int st = partial[blockIdx.x] + s[threadIdx.x] - v;  // exclusive
        starts[i] = st; cursor[i] = st;
    }
    if (i == 0) starts[N_NODES] = N_EDGES;
}

// scatter edges into CSR order; record packed to 4B: (col<<16) | t_fix9.7
__global__ void k_scatter(const int* __restrict__ row, const int* __restrict__ col,
                          const float* __restrict__ pos, int* __restrict__ cursor,
                          unsigned int* __restrict__ erec) {
    int e = blockIdx.x * blockDim.x + threadIdx.x;
    if (e >= N_EDGES) return;
    int r = row[e], c = col[e];
    int p = atomicAdd(&cursor[r], 1);
    float dx = pos[c * 3 + 0] - pos[r * 3 + 0];
    float dy = pos[c * 3 + 1] - pos[r * 3 + 1];
    float dz = pos[c * 3 + 2] - pos[r * 3 + 2];
    float len = sqrtf(dx * dx + dy * dy + dz * dz);
    float t = len * ((float)(TLUT - 1) / CUT_R);
    t = fminf(t, (float)(TLUT - 1));        // exact for len>=cutoff (rbf==0 there)
    unsigned int tfix = (unsigned int)(t * 128.0f);   // 9.7 fixed point, <= 65408
    erec[p] = ((unsigned int)c << 16) | tfix;
}

// W2s[l][k][h] = sum_{m<3} rad_w2[l][k][h*3+m]; Wsp[l][k][h] = (self_w @ proj_top)[k][h]
__global__ void k_prep(const float* __restrict__ rad_w2, const float* __restrict__ self_w,
                       const float* __restrict__ proj_w,
                       float* __restrict__ W2s, float* __restrict__ Wsp) {
    int i = blockIdx.x * blockDim.x + threadIdx.x;          // L*H*H
    if (i >= NLAYER * HDIM * HDIM) return;
    int l = i / (HDIM * HDIM); int rem = i % (HDIM * HDIM);
    int k = rem / HDIM; int h = rem % HDIM;
    const float* w = rad_w2 + ((size_t)l * HDIM + k) * (HDIM * 3) + h * 3;
    W2s[i] = w[0] + w[1] + w[2];
    const float* sw = self_w + ((size_t)l * HDIM + k) * HDIM;
    const float* pw = proj_w + (size_t)l * 2 * HDIM * HDIM;
    float acc = 0.f;
    for (int m = 0; m < HDIM; ++m) acc += sw[m] * pw[m * HDIM + h];
    Wsp[i] = acc;
}

// b2s[l][h] = sum_m rad_b2[l][h*3+m];  bsp[l][h] = self_b@proj_top + proj_b
__global__ void k_bias(const float* __restrict__ rad_b2, const float* __restrict__ self_b,
                       const float* __restrict__ proj_w, const float* __restrict__ proj_b,
                       float* __restrict__ b2s, float* __restrict__ bsp) {
    int i = blockIdx.x * blockDim.x + threadIdx.x;          // L*H
    if (i >= NLAYER * HDIM) return;
    int l = i / HDIM, h = i % HDIM;
    const float* rb2 = rad_b2 + l * HDIM * 3 + h * 3;
    b2s[i] = rb2[0] + rb2[1] + rb2[2];
    float acc = proj_b[l * HDIM + h];
    const float* pw = proj_w + (size_t)l * 2 * HDIM * HDIM;
    const float* sb = self_b + l * HDIM;
    for (int m = 0; m < HDIM; ++m) acc += sb[m] * pw[m * HDIM + h];
    bsp[i] = acc;
}

// radial LUT: lut[l][t][h] = (silu(rbf(len_t)@W1 + b1) @ W2s + b2s)[h]
__global__ void k_lut(const float* __restrict__ widths, const float* __restrict__ rad_w1,
                      const float* __restrict__ rad_b1, const float* __restrict__ W2s,
                      const float* __restrict__ b2s, float* __restrict__ lut) {
    int bid = blockIdx.x;                 // l*TLUT + t
    int l = bid / TLUT, t = bid % TLUT;
    int h = threadIdx.x;                  // 64 threads
    __shared__ float h1s[HDIM];
    float len = (float)t * (CUT_R / (float)(TLUT - 1));
    float cut = 0.0f;
    if (len < CUT_R) cut = 0.5f * (cosf(len * (PI_F / CUT_R)) + 1.0f);
    float acc = rad_b1[l * HDIM + h];
    for (int b = 0; b < NBASIS; ++b) {
        float wb = fmaxf(widths[b], 0.1f);
        float center = (float)b * (CUT_R / (float)(NBASIS - 1));
        float d = (len - center) / wb;
        float rbf = __expf(-0.5f * d * d) * cut;
        acc += rbf * rad_w1[(l * NBASIS + b) * HDIM + h];
    }
    h1s[h] = siluf(acc);
    __syncthreads();
    float o = b2s[l * HDIM + h];
    const float* w2 = W2s + (size_t)l * HDIM * HDIM;
    for (int k = 0; k < HDIM; ++k) o += h1s[k] * w2[k * HDIM + h];
    lut[(size_t)bid * HDIM + h] = o;
}

// lutQ[(l*TLUT+t)*16+j] = pair {row t ch 4j..4j+3, row t+1 ch 4j..4j+3}
__global__ void k_lutq(const float* __restrict__ lut, float4* __restrict__ lutQ) {
    int i = blockIdx.x * blockDim.x + threadIdx.x;          // L*TLUT*16
    if (i >= NLAYER * TLUT * 16) return;
    int j = i & 15;
    int lt = i >> 4;                       // l*TLUT + t
    int l = lt / TLUT, t = lt % TLUT;
    int t1 = (t < TLUT - 1) ? t + 1 : t;
    const float* r0 = lut + (size_t)(l * TLUT + t)  * HDIM + 4 * j;
    const float* r1 = lut + (size_t)(l * TLUT + t1) * HDIM + 4 * j;
    lutQ[(size_t)i * 2 + 0] = make_float4(r0[0], r0[1], r0[2], r0[3]);
    lutQ[(size_t)i * 2 + 1] = make_float4(r1[0], r1[1], r1[2], r1[3]);
}

// ---------------- per-layer kernels ----------------

// one wave per node, 4 edge slots x 16 lanes (4 channels each via float4)
__global__ __launch_bounds__(256) void k_agg(const float4* __restrict__ feats4,
                                             const float4* __restrict__ lutQ_l,
                                             const int* __restrict__ starts,
                                             const unsigned int* __restrict__ erec,
                                             float4* __restrict__ agg4) {
    int wid  = (blockIdx.x * blockDim.x + threadIdx.x) >> 6;
    int lane = threadIdx.x & 63;
    int slot = lane >> 4;
    int j    = lane & 15;
    if (wid >= N_NODES) return;
    int e0 = starts[wid], e1 = starts[wid + 1];
    float ax = 0.f, ay = 0.f, az = 0.f, aw = 0.f;
    #pragma unroll 2
    for (int e = e0 + slot; e < e1; e += 4) {
        unsigned int rec = erec[e];
        int c    = rec >> 16;
        int tfix = rec & 0xffff;
        int i0   = tfix >> 7;
        float f  = (float)(tfix & 127) * (1.0f / 128.0f);
        const float4* q = lutQ_l + ((size_t)(i0 * 16 + j) * 2);
        float4 w0 = q[0];
        float4 w1 = q[1];
        float4 fv = feats4[(size_t)c * 16 + j];
        ax += fv.x * (w0.x + f * (w1.x - w0.x));
        ay += fv.y * (w0.y + f * (w1.y - w0.y));
        az += fv.z * (w0.z + f * (w1.z - w0.z));
        aw += fv.w * (w0.w + f * (w1.w - w0.w));
    }
    // reduce across the 4 slots (lanes j, j+16, j+32, j+48)
    ax += __shfl_xor(ax, 16, 64);  ay += __shfl_xor(ay, 16, 64);
    az += __shfl_xor(az, 16, 64);  aw += __shfl_xor(aw, 16, 64);
    ax += __shfl_xor(ax, 32, 64);  ay += __shfl_xor(ay, 32, 64);
    az += __shfl_xor(az, 32, 64);  aw += __shfl_xor(aw, 32, 64);
    if (slot == 0) agg4[(size_t)wid * 16 + j] = make_float4(ax, ay, az, aw);
}

// 4 waves/block, 16 nodes per wave; lane = output channel. Weights in per-lane
// VGPR arrays (static index); matmul k-operands via wave-uniform ds_read_b128
// broadcasts from a private 8KB LDS region per wave. No __syncthreads needed.
constexpr int NPW = 16;                    // nodes per wave
__global__ __launch_bounds__(256) void k_node(float* __restrict__ feats,
        const float* __restrict__ agg,
        const float* __restrict__ Wsp_l, const float* __restrict__ bsp_l,
        const float* __restrict__ projw_l,
        const float* __restrict__ mlp_w1_l, const float* __restrict__ mlp_b1_l,
        const float* __restrict__ mlp_w2_l, const float* __restrict__ mlp_b2_l,
        const float* __restrict__ ln_g_l, const float* __restrict__ ln_b_l) {
    __shared__ float Tall[4 * 2 * NPW * 64];   // 32 KB (4 waves x 8 KB)
    const int lane = threadIdx.x & 63;
    const int wib  = threadIdx.x >> 6;
    float* T = Tall + wib * (2 * NPW * 64);
    const int nb0 = blockIdx.x * (4 * NPW) + wib * NPW;
    const float* pb = projw_l + HDIM * HDIM;   // bottom half of proj_w

    // stage x (rows 0..15) and a (rows 16..31); coalesced, 2-way bank (free)
    #pragma unroll 4
    for (int r = 0; r < NPW; ++r) {
        int nd = nb0 + r; nd = (nd < N_NODES) ? nd : (N_NODES - 1);
        T[r * 64 + lane]         = feats[(size_t)nd * 64 + lane];
        T[(NPW + r) * 64 + lane] = agg[(size_t)nd * 64 + lane];
    }

    // conv weights: per-lane columns, static-index register arrays
    float Wa[64], Wb[64];
    #pragma unroll
    for (int k = 0; k < 64; ++k) Wa[k] = Wsp_l[k * 64 + lane];
    #pragma unroll
    for (int k = 0; k < 64; ++k) Wb[k] = pb[k * 64 + lane];
    float bspv = bsp_l[lane];

    asm volatile("s_waitcnt lgkmcnt(0)" ::: "memory");

    // conv = bsp + x@Wsp + a@Pb -> store over a-rows (16..31)
    #pragma unroll 1
    for (int r0 = 0; r0 < NPW; r0 += 4) {
        float c0 = bspv, c1 = bspv, c2 = bspv, c3 = bspv;
        #pragma unroll
        for (int k = 0; k < 64; k += 4) {
            float4 x0 = *(const float4*)&T[(r0 + 0) * 64 + k];
            float4 x1 = *(const float4*)&T[(r0 + 1) * 64 + k];
            float4 x2 = *(const float4*)&T[(r0 + 2) * 64 + k];
            float4 x3 = *(const float4*)&T[(r0 + 3) * 64 + k];
            c0 = fmaf(x0.x, Wa[k], c0); c0 = fmaf(x0.y, Wa[k+1], c0); c0 = fmaf(x0.z, Wa[k+2], c0); c0 = fmaf(x0.w, Wa[k+3], c0);
            c1 = fmaf(x1.x, Wa[k], c1); c1 = fmaf(x1.y, Wa[k+1], c1); c1 = fmaf(x1.z, Wa[k+2], c1); c1 = fmaf(x1.w, Wa[k+3], c1);
            c2 = fmaf(x2.x, Wa[k], c2); c2 = fmaf(x2.y, Wa[k+1], c2); c2 = fmaf(x2.z, Wa[k+2], c2); c2 = fmaf(x2.w, Wa[k+3], c2);
            c3 = fmaf(x3.x, Wa[k], c3); c3 = fmaf(x3.y, Wa[k+1], c3); c3 = fmaf(x3.z, Wa[k+2], c3); c3 = fmaf(x3.w, Wa[k+3], c3);
        }
        #pragma unroll
        for (int k = 0; k < 64; k += 4) {
            float4 a0 = *(const float4*)&T[(NPW + r0 + 0) * 64 + k];
            float4 a1 = *(const float4*)&T[(NPW + r0 + 1) * 64 + k];
            float4 a2 = *(const float4*)&T[(NPW + r0 + 2) * 64 + k];
            float4 a3 = *(const float4*)&T[(NPW + r0 + 3) * 64 + k];
            c0 = fmaf(a0.x, Wb[k], c0); c0 = fmaf(a0.y, Wb[k+1], c0); c0 = fmaf(a0.z, Wb[k+2], c0); c0 = fmaf(a0.w, Wb[k+3], c0);
            c1 = fmaf(a1.x, Wb[k], c1); c1 = fmaf(a1.y, Wb[k+1], c1); c1 = fmaf(a1.z, Wb[k+2], c1); c1 = fmaf(a1.w, Wb[k+3], c1);
            c2 = fmaf(a2.x, Wb[k], c2); c2 = fmaf(a2.y, Wb[k+1], c2); c2 = fmaf(a2.z, Wb[k+2], c2); c2 = fmaf(a2.w, Wb[k+3], c2);
            c3 = fmaf(a3.x, Wb[k], c3); c3 = fmaf(a3.y, Wb[k+1], c3); c3 = fmaf(a3.z, Wb[k+2], c3); c3 = fmaf(a3.w, Wb[k+3], c3);
        }
        T[(NPW + r0 + 0) * 64 + lane] = c0;
        T[(NPW + r0 + 1) * 64 + lane] = c1;
        T[(NPW + r0 + 2) * 64 + lane] = c2;
        T[(NPW + r0 + 3) * 64 + lane] = c3;
    }

    // mlp1 weights (reuse Wa/Wb register budget)
    float W1a[64], W1b[64];
    #pragma unroll
    for (int k = 0; k < 64; ++k) W1a[k] = mlp_w1_l[k * 128 + lane];
    #pragma unroll
    for (int k = 0; k < 64; ++k) W1b[k] = mlp_w1_l[k * 128 + 64 + lane];
    float b1a = mlp_b1_l[lane], b1b = mlp_b1_l[64 + lane];

    asm volatile("s_waitcnt lgkmcnt(0)" ::: "memory");

    // m1 = silu(conv@W1 + b1): node r -> row r (ch 0..63) and row NPW+r (ch 64..127)
    #pragma unroll 1
    for (int r0 = 0; r0 < NPW; r0 += 2) {
        float m00 = b1a, m01 = b1b, m10 = b1a, m11 = b1b;
        #pragma unroll
        for (int k = 0; k < 64; k += 4) {
            float4 x0 = *(const float4*)&T[(NPW + r0 + 0) * 64 + k];
            float4 x1 = *(const float4*)&T[(NPW + r0 + 1) * 64 + k];
            m00 = fmaf(x0.x, W1a[k], m00); m00 = fmaf(x0.y, W1a[k+1], m00); m00 = fmaf(x0.z, W1a[k+2], m00); m00 = fmaf(x0.w, W1a[k+3], m00);
            m01 = fmaf(x0.x, W1b[k], m01); m01 = fmaf(x0.y, W1b[k+1], m01); m01 = fmaf(x0.z, W1b[k+2], m01); m01 = fmaf(x0.w, W1b[k+3], m01);
            m10 = fmaf(x1.x, W1a[k], m10); m10 = fmaf(x1.y, W1a[k+1], m10); m10 = fmaf(x1.z, W1a[k+2], m10); m10 = fmaf(x1.w, W1a[k+3], m10);
            m11 = fmaf(x1.x, W1b[k], m11); m11 = fmaf(x1.y, W1b[k+1], m11); m11 = fmaf(x1.z, W1b[k+2], m11); m11 = fmaf(x1.w, W1b[k+3], m11);
        }
        T[(r0 + 0) * 64 + lane]       = siluf(m00);
        T[(NPW + r0 + 0) * 64 + lane] = siluf(m01);
        T[(r0 + 1) * 64 + lane]       = siluf(m10);
        T[(NPW + r0 + 1) * 64 + lane] = siluf(m11);
    }

    // mlp2 weights
    float W2c[128];
    #pragma unroll
    for (int k = 0; k < 128; ++k) W2c[k] = mlp_w2_l[k * 64 + lane];
    float b2v = mlp_b2_l[lane];
    float gv  = ln_g_l[lane], bv = ln_b_l[lane];

    asm volatile("s_waitcnt lgkmcnt(0)" ::: "memory");

    // upd = m1@W2 + b2; then residual + LayerNorm, write feats
    #pragma unroll 1
    for (int r0 = 0; r0 < NPW; r0 += 2) {
        float u0 = b2v, u1 = b2v;
        #pragma unroll
        for (int k = 0; k < 64; k += 4) {
            float4 x0 = *(const float4*)&T[(r0 + 0) * 64 + k];
            float4 x1 = *(const float4*)&T[(r0 + 1) * 64 + k];
            u0 = fmaf(x0.x, W2c[k], u0); u0 = fmaf(x0.y, W2c[k+1], u0); u0 = fmaf(x0.z, W2c[k+2], u0); u0 = fmaf(x0.w, W2c[k+3], u0);
            u1 = fmaf(x1.x, W2c[k], u1); u1 = fmaf(x1.y, W2c[k+1], u1); u1 = fmaf(x1.z, W2c[k+2], u1); u1 = fmaf(x1.w, W2c[k+3], u1);
        }
        #pragma unroll
        for (int k = 0; k < 64; k += 4) {
            float4 x0 = *(const float4*)&T[(NPW + r0 + 0) * 64 + k];
            float4 x1 = *(const float4*)&T[(NPW + r0 + 1) * 64 + k];
            u0 = fmaf(x0.x, W2c[64+k], u0); u0 = fmaf(x0.y, W2c[64+k+1], u0); u0 = fmaf(x0.z, W2c[64+k+2], u0); u0 = fmaf(x0.w, W2c[64+k+3], u0);
            u1 = fmaf(x1.x, W2c[64+k], u1); u1 = fmaf(x1.y, W2c[64+k+1], u1); u1 = fmaf(x1.z, W2c[64+k+2], u1); u1 = fmaf(x1.w, W2c[64+k+3], u1);
        }
        int nd0 = nb0 + r0, nd1 = nb0 + r0 + 1;
        int nd0s = (nd0 < N_NODES) ? nd0 : (N_NODES - 1);
        int nd1s = (nd1 < N_NODES) ? nd1 : (N_NODES - 1);
        float y0 = feats[(size_t)nd0s * 64 + lane] + u0;
        float y1 = feats[(size_t)nd1s * 64 + lane] + u1;
        float p0 = y0, q0 = y0 * y0, p1 = y1, q1 = y1 * y1;
        #pragma unroll
        for (int off = 32; off > 0; off >>= 1) {
            p0 += __shfl_xor(p0, off, 64);  q0 += __shfl_xor(q0, off, 64);
            p1 += __shfl_xor(p1, off, 64);  q1 += __shfl_xor(q1, off, 64);
        }
        float mu0 = p0 * (1.0f / 64.0f), var0 = q0 * (1.0f / 64.0f) - mu0 * mu0;
        float mu1 = p1 * (1.0f / 64.0f), var1 = q1 * (1.0f / 64.0f) - mu1 * mu1;
        float rr0 = rsqrtf(var0 + 1e-5f), rr1 = rsqrtf(var1 + 1e-5f);
        if (nd0 < N_NODES) feats[(size_t)nd0 * 64 + lane] = (y0 - mu0) * rr0 * gv + bv;
        if (nd1 < N_NODES) feats[(size_t)nd1 * 64 + lane] = (y1 - mu1) * rr1 * gv + bv;
    }
}

// ---------------- readout ----------------

__global__ __launch_bounds__(256) void k_readout(const float* __restrict__ feats,
        const int* __restrict__ an,
        const float* __restrict__ ro_w1, const float* __restrict__ ro_b1,
        const float* __restrict__ ro_w2, const float* __restrict__ ro_b2,
        const float* __restrict__ ro_w3, const float* __restrict__ ro_b3,
        const float* __restrict__ atomic_e, float* __restrict__ blockpart) {
    __shared__ float sacc[4];
    int wib  = threadIdx.x >> 6;
    int lane = threadIdx.x & 63;
    int node = blockIdx.x * 4 + wib;
    float e = 0.0f;
    if (node < N_NODES) {
        float x = feats[(size_t)node * HDIM + lane];
        float h1 = ro_b1[lane];
        #pragma unroll 8
        for (int k = 0; k < HDIM; ++k) h1 += bcastf(x, k) * ro_w1[k * HDIM + lane];
        h1 = siluf(h1);
        int j = lane & 31;
        float h2 = ro_b2[j];
        #pragma unroll 8
        for (int k = 0; k < HDIM; ++k) h2 += bcastf(h1, k) * ro_w2[k * 32 + j];
        h2 = siluf(h2);
        float contrib = (lane < 32) ? h2 * ro_w3[j] : 0.0f;
        contrib = waveRedSum(contrib);
        e = contrib + ro_b3[0] + atomic_e[an[node]];
    }
    if (lane == 0) sacc[wib] = e;
    __syncthreads();
    if (threadIdx.x == 0)
        blockpart[blockIdx.x] = sacc[0] + sacc[1] + sacc[2] + sacc[3];
}

__global__ void k_final(const float* __restrict__ blockpart, int nb, float* __restrict__ out) {
    __shared__ float s[256];
    float acc = 0.f;
    for (int i = threadIdx.x; i < nb; i += 256) acc += blockpart[i];
    s[threadIdx.x] = acc; __syncthreads();
    for (int off = 128; off > 0; off >>= 1) {
        if (threadIdx.x < off) s[threadIdx.x] += s[threadIdx.x + off];
        __syncthreads();
    }
    if (threadIdx.x == 0) out[0] = s[0];
}

// ---------------- launch ----------------

extern "C" void kernel_launch(void* const* d_in, const int* in_sizes, int n_in,
                              void* d_out, int out_size, void* d_ws, size_t ws_size,
                              hipStream_t stream) {
    const int*   an       = (const int*)  d_in[0];
    const float* pos      = (const float*)d_in[1];
    const int*   edge     = (const int*)  d_in[2];
    const float* widths   = (const float*)d_in[3];
    const float* embed    = (const float*)d_in[4];
    const float* rad_w1   = (const float*)d_in[5];
    const float* rad_b1   = (const float*)d_in[6];
    const float* rad_w2   = (const float*)d_in[7];
    const float* rad_b2   = (const float*)d_in[8];
    const float* self_w   = (const float*)d_in[9];
    const float* self_b   = (const float*)d_in[10];
    const float* proj_w   = (const float*)d_in[11];
    const float* proj_b   = (const float*)d_in[12];
    const float* mlp_w1   = (const float*)d_in[13];
    const float* mlp_b1   = (const float*)d_in[14];
    const float* mlp_w2   = (const float*)d_in[15];
    const float* mlp_b2   = (const float*)d_in[16];
    const float* ln_g     = (const float*)d_in[17];
    const float* ln_b     = (const float*)d_in[18];
    const float* ro_w1    = (const float*)d_in[19];
    const float* ro_b1    = (const float*)d_in[20];
    const float* ro_w2    = (const float*)d_in[21];
    const float* ro_b2    = (const float*)d_in[22];
    const float* ro_w3    = (const float*)d_in[23];
    const float* ro_b3    = (const float*)d_in[24];
    const float* atomic_e = (const float*)d_in[25];

    char* w = (char*)d_ws;
    auto alloc = [&](size_t bytes) { char* p = w; w += (bytes + 255) & ~(size_t)255; return p; };
    float* feats     = (float*)alloc(sizeof(float) * N_NODES * HDIM);
    float* aggb      = (float*)alloc(sizeof(float) * N_NODES * HDIM);
    float* lut       = (float*)alloc(sizeof(float) * NLAYER * TLUT * HDIM);
    float4* lutQ     = (float4*)alloc(sizeof(float4) * NLAYER * TLUT * 32);
    float* W2s       = (float*)alloc(sizeof(float) * NLAYER * HDIM * HDIM);
    float* b2s       = (float*)alloc(sizeof(float) * NLAYER * HDIM);
    float* Wsp       = (float*)alloc(sizeof(float) * NLAYER * HDIM * HDIM);
    float* bsp       = (float*)alloc(sizeof(float) * NLAYER * HDIM);
    unsigned int* erec = (unsigned int*)alloc(sizeof(unsigned int) * N_EDGES);
    int*   starts    = (int*)  alloc(sizeof(int) * (N_NODES + 1));
    int*   cursor    = (int*)  alloc(sizeof(int) * N_NODES);
    int*   counts    = (int*)  alloc(sizeof(int) * N_NODES);
    int*   partial   = (int*)  alloc(sizeof(int) * 256);
    float* blockpart = (float*)alloc(sizeof(float) * 12500);
    (void)ws_size; (void)in_sizes; (void)n_in; (void)out_size;

    const int* erow = edge;
    const int* ecol = edge + N_EDGES;

    hipMemsetAsync(counts, 0, sizeof(int) * N_NODES, stream);
    k_embed<<<12500, 256, 0, stream>>>(an, embed, feats);
    k_hist<<<6250, 256, 0, stream>>>(erow, counts);
    k_scan1<<<196, 256, 0, stream>>>(counts, partial);
    k_scan2<<<1, 256, 0, stream>>>(partial, 196);
    k_scan3<<<196, 256, 0, stream>>>(counts, partial, starts, cursor);
    k_scatter<<<6250, 256, 0, stream>>>(erow, ecol, pos, cursor, erec);
    k_prep<<<80, 256, 0, stream>>>(rad_w2, self_w, proj_w, W2s, Wsp);
    k_bias<<<5, 64, 0, stream>>>(rad_b2, self_b, proj_w, proj_b, b2s, bsp);
    k_lut<<<NLAYER * TLUT, 64, 0, stream>>>(widths, rad_w1, rad_b1, W2s, b2s, lut);
    k_lutq<<<(NLAYER * TLUT * 16 + 255) / 256, 256, 0, stream>>>(lut, lutQ);

    for (int l = 0; l < NLAYER; ++l) {
        k_agg<<<12500, 256, 0, stream>>>((const float4*)feats,
                                         lutQ + (size_t)l * TLUT * 32,
                                         starts, erec, (float4*)aggb);
        k_node<<<782, 256, 0, stream>>>(feats, aggb,
            Wsp + (size_t)l * HDIM * HDIM, bsp + l * HDIM,
            proj_w + (size_t)l * 2 * HDIM * HDIM,
            mlp_w1 + (size_t)l * HDIM * 2 * HDIM, mlp_b1 + l * 2 * HDIM,
            mlp_w2 + (size_t)l * 2 * HDIM * HDIM, mlp_b2 + l * HDIM,
            ln_g + l * HDIM, ln_b + l * HDIM);
    }

    k_readout<<<12500, 256, 0, stream>>>(feats, an, ro_w1, ro_b1, ro_w2, ro_b2,
                                         ro_w3, ro_b3, atomic_e, blockpart);
    k_final<<<1, 256, 0, stream>>>(blockpart, 12500, (float*)d_out);
}